// Round 21
// baseline (134.754 us; speedup 1.0000x reference)
//
#include <hip/hip_runtime.h>
#include <hip/hip_bf16.h>

typedef __bf16 bf16;
typedef bf16 bf16x4 __attribute__((ext_vector_type(4)));
typedef bf16 bf16x8 __attribute__((ext_vector_type(8)));
typedef float f32x4 __attribute__((ext_vector_type(4)));
typedef float f32x16 __attribute__((ext_vector_type(16)));
typedef unsigned int u32x4 __attribute__((ext_vector_type(4)));

#define LOG2E 1.44269504088896340736f

__device__ __forceinline__ void gload_lds16(const bf16* g, bf16* l) {
  __builtin_amdgcn_global_load_lds(
      (const __attribute__((address_space(1))) void*)g,
      (__attribute__((address_space(3))) void*)l, 16, 0, 0);
}

// raw v_exp_f32 (2^x): args here are always <= ~8, -inf ok (-> 0)
__device__ __forceinline__ float fexp2(float x) {
  float r;
  asm("v_exp_f32 %0, %1" : "=v"(r) : "v"(x));
  return r;
}

// ---------------- fp32 -> bf16 conversion (5 segments in one launch) -------
struct CvtArgs {
  const float* src[5];
  bf16* dst[5];
  int n[5];
};

__global__ __launch_bounds__(256) void cvt_multi(CvtArgs a) {
  const int seg = blockIdx.y;
  const float* __restrict__ s = a.src[seg];
  bf16* __restrict__ d = a.dst[seg];
  const int n = a.n[seg];
  int i = (blockIdx.x * 256 + threadIdx.x) * 4;
  const int stride = gridDim.x * 256 * 4;
  for (; i < n; i += stride) {
    float4 f = *reinterpret_cast<const float4*>(s + i);
    bf16x4 o = {(bf16)f.x, (bf16)f.y, (bf16)f.z, (bf16)f.w};
    *reinterpret_cast<bf16x4*>(d + i) = o;
  }
}

// ---------------- 128x128 bf16 GEMM (BK=64), C = A * B^T + bias ------------
// BK=64 (r18: -4us vs BK=32 -- halves per-iteration vmcnt(0)+barrier drains).
struct GemmBatch {
  const bf16* Bw[3];
  const float* bias[3];
  void* C[3];
};

template <bool OUT_BF16>
__global__ __launch_bounds__(256, 2) void gemm128(const bf16* __restrict__ A,
                                                  GemmBatch gb, int M, int N,
                                                  int K) {
  const int tid = threadIdx.x;
  const int wid = tid >> 6;
  const int lane = tid & 63;
  const int l16 = lane & 15;
  const int hi = lane >> 4;
  const int m0 = blockIdx.x * 128;
  const int n0 = blockIdx.y * 128;
  const int z = blockIdx.z;
  const bf16* __restrict__ Bw = gb.Bw[z];
  const float* __restrict__ bias = gb.bias[z];

  __shared__ bf16 As[128 * 64];
  __shared__ bf16 Bs[128 * 64];

  f32x4 acc[4][4] = {};

  const int wm = (wid >> 1) * 64;
  const int wn = (wid & 1) * 64;

  for (int k0 = 0; k0 < K; k0 += 64) {
#pragma unroll
    for (int i = 0; i < 4; ++i) {
      const int chunk = wid + 4 * i;               // 0..15, wave-uniform
      const int p = chunk * 1024 + lane * 16;      // physical LDS byte
      const int row = p >> 7;                      // 128B per row (64 bf16)
      const int cb = (p & 112) ^ ((row & 3) << 4); // logical col byte
      gload_lds16(A + (size_t)(m0 + row) * K + k0 + (cb >> 1), As + chunk * 512);
      gload_lds16(Bw + (size_t)(n0 + row) * K + k0 + (cb >> 1), Bs + chunk * 512);
    }
    __syncthreads();

#pragma unroll
    for (int ks = 0; ks < 2; ++ks) {
      bf16x8 af[4], bfr[4];
#pragma unroll
      for (int m = 0; m < 4; ++m) {
        const int r = wm + m * 16 + l16;
        const int pb = r * 128 + ((ks * 64 + hi * 16) ^ ((r & 3) << 4));
        af[m] = *reinterpret_cast<const bf16x8*>((const char*)As + pb);
      }
#pragma unroll
      for (int n = 0; n < 4; ++n) {
        const int r = wn + n * 16 + l16;
        const int pb = r * 128 + ((ks * 64 + hi * 16) ^ ((r & 3) << 4));
        bfr[n] = *reinterpret_cast<const bf16x8*>((const char*)Bs + pb);
      }
#pragma unroll
      for (int m = 0; m < 4; ++m)
#pragma unroll
        for (int n = 0; n < 4; ++n)
          acc[m][n] =
              __builtin_amdgcn_mfma_f32_16x16x32_bf16(af[m], bfr[n], acc[m][n], 0, 0, 0);
    }
    __syncthreads();
  }

  const int rbase = m0 + wm + hi * 4;
  const int cbase = n0 + wn + l16;
#pragma unroll
  for (int n = 0; n < 4; ++n) {
    const int col = cbase + n * 16;
    const float bv = bias[col];
#pragma unroll
    for (int m = 0; m < 4; ++m) {
#pragma unroll
      for (int j = 0; j < 4; ++j) {
        const int row = rbase + m * 16 + j;
        const float v = acc[m][n][j] + bv;
        if (OUT_BF16)
          ((bf16*)gb.C[z])[(size_t)row * N + col] = (bf16)v;
        else
          ((float*)gb.C[z])[(size_t)row * N + col] = v;
      }
    }
  }
}

// ---------------- causal flash attention, 4 q-sets/wave, 128q x 64kv -------
// r21: FOUR 32-row q-sets per wave (r13's proven ILP lever, doubled again).
// Residency is grid-limited at 2 waves/SIMD, so VGPR up to 256 is free --
// more independent MFMA chains per wave is the only mechanism that has
// paid (r13 +50%); staging/softmax amortization (r17) and prefetch pinning
// (r11/r12) were nulls, extra waves (r19) regressed.
// 512 unpaired blocks big-first: block p = (b,h)=p&31, qg128 g=15-(p>>5).
// Per kv64 tile: one stageV + one kr[8] shared by 4 sets; qf reloaded per
// set from L1 (saves 48 VGPR). Set s diag tile dt=2g+(s>>1); diag in low
// half if s even (skip high), in high half if s odd.
__global__ __launch_bounds__(256, 2) void attn_ws(const bf16* __restrict__ Q,
                                                  const bf16* __restrict__ K,
                                                  const bf16* __restrict__ V,
                                                  bf16* __restrict__ Y) {
  const int p = blockIdx.x;    // 0..511
  const int bh = p & 31;       // XCD p%8 sees streams {bh : bh%8 == p%8}
  const int g = 15 - (p >> 5); // 0..15, big-first
  const int h = bh & 15;
  const int b = bh >> 4;

  const int tid = threadIdx.x;
  const int w = tid >> 6;
  const int lane = tid & 63;
  const int l31 = lane & 31;
  const int hi2 = lane >> 5;
  const size_t rb = (size_t)b * 2048;
  const int hcol = h * 64;
  const float cl2 = 0.125f * LOG2E;

  // Vt: 4 per-wave [64][72] bf16 slices (36864 B); comb quarter [4][32][34]
  // f32 (17408 B) aliases it, time-separated by barriers.
  __shared__ char smem[36864];
  __shared__ float mlS[4][2][128];
  bf16(*Vt)[72] = (bf16(*)[72])(smem + (size_t)w * 9216);
  float* combf = (float*)smem;

  const int kvg = lane & 7;   // staging: kv quad group
  const int dgr = lane >> 3;  // staging: d quad group (0..7)

  auto stageV = [&](int tt) {
    const bf16* vp0 = V + (rb + tt * 64 + kvg * 4) * 1024 + hcol + dgr * 4;
#pragma unroll
    for (int hh = 0; hh < 2; ++hh) {
      const bf16* vp = vp0 + (size_t)hh * 32 * 1024;
      bf16x4 vr[2][4];
#pragma unroll
      for (int r = 0; r < 2; ++r)
#pragma unroll
        for (int jj = 0; jj < 4; ++jj)
          vr[r][jj] = *reinterpret_cast<const bf16x4*>(vp + (size_t)jj * 1024 + r * 32);
#pragma unroll
      for (int r = 0; r < 2; ++r)
#pragma unroll
        for (int kc = 0; kc < 4; ++kc) {
          bf16x4 wv = {vr[r][0][kc], vr[r][1][kc], vr[r][2][kc], vr[r][3][kc]};
          *reinterpret_cast<bf16x4*>(&Vt[r * 32 + dgr * 4 + kc][hh * 32 + kvg * 4]) = wv;
        }
    }
  };

  const int qbase = g * 128;
  const int NT = 2 * g + 2;  // kv tiles of 64

  // set-s q rows start at qbase + s*32; frag base pointer (per-lane)
  const bf16* qp0 = Q + (rb + qbase + l31) * 1024 + hcol + hi2 * 8;

  f32x16 y[4][2] = {};  // [set][d-half]; all indexing via unrolled consts
  float m[4], l[4];
#pragma unroll
  for (int s = 0; s < 4; ++s) {
    m[s] = -INFINITY;
    l[s] = 0.f;
  }

  auto smax_pv64 = [&](f32x16& s0, f32x16& s1, float& mm, float& ll,
                       f32x16& y0, f32x16& y1, bool skipHi) {
    float red[8];
#pragma unroll
    for (int i = 0; i < 8; ++i)
      red[i] = fmaxf(fmaxf(s0[i], s0[i + 8]), fmaxf(s1[i], s1[i + 8]));
#pragma unroll
    for (int i = 0; i < 4; ++i) red[i] = fmaxf(red[i], red[i + 4]);
    float pm = fmaxf(fmaxf(red[0], red[1]), fmaxf(red[2], red[3]));
    pm = fmaxf(pm, __shfl_xor(pm, 32));

    if (!__all(pm <= mm + 40.f)) {  // defer-max (T13)
      const float mn = fmaxf(mm, pm);
      const float al = fexp2((mm - mn) * cl2);
#pragma unroll
      for (int r = 0; r < 16; ++r) {
        y0[r] *= al;
        y1[r] *= al;
      }
      ll *= al;
      mm = mn;
    }
    const float mc = mm * cl2;
    float ps[32];
#pragma unroll
    for (int r = 0; r < 16; ++r) ps[r] = fexp2(s0[r] * cl2 - mc);
#pragma unroll
    for (int r = 0; r < 16; ++r) ps[16 + r] = fexp2(s1[r] * cl2 - mc);
    float sum[16];
#pragma unroll
    for (int i = 0; i < 16; ++i) sum[i] = ps[i] + ps[i + 16];
#pragma unroll
    for (int i = 0; i < 8; ++i) sum[i] += sum[i + 8];
#pragma unroll
    for (int i = 0; i < 4; ++i) sum[i] += sum[i + 4];
    float rs = (sum[0] + sum[1]) + (sum[2] + sum[3]);
    rs += __shfl_xor(rs, 32);
    ll += rs;

    unsigned int pk[16];
#pragma unroll
    for (int i = 0; i < 16; ++i) {
      const unsigned short a = __builtin_bit_cast(unsigned short, (bf16)ps[2 * i]);
      const unsigned short c = __builtin_bit_cast(unsigned short, (bf16)ps[2 * i + 1]);
      pk[i] = (unsigned int)a | ((unsigned int)c << 16);
    }
    asm("v_permlane32_swap_b32 %0, %1" : "+v"(pk[0]), "+v"(pk[2]));
    asm("v_permlane32_swap_b32 %0, %1" : "+v"(pk[1]), "+v"(pk[3]));
    asm("v_permlane32_swap_b32 %0, %1" : "+v"(pk[4]), "+v"(pk[6]));
    asm("v_permlane32_swap_b32 %0, %1" : "+v"(pk[5]), "+v"(pk[7]));
    asm("v_permlane32_swap_b32 %0, %1" : "+v"(pk[8]), "+v"(pk[10]));
    asm("v_permlane32_swap_b32 %0, %1" : "+v"(pk[9]), "+v"(pk[11]));
    asm("v_permlane32_swap_b32 %0, %1" : "+v"(pk[12]), "+v"(pk[14]));
    asm("v_permlane32_swap_b32 %0, %1" : "+v"(pk[13]), "+v"(pk[15]));
    const u32x4 f0 = {pk[0], pk[1], pk[2], pk[3]};
    const u32x4 f1 = {pk[4], pk[5], pk[6], pk[7]};
    const u32x4 f2 = {pk[8], pk[9], pk[10], pk[11]};
    const u32x4 f3 = {pk[12], pk[13], pk[14], pk[15]};
    const bf16x8 pa0 = __builtin_bit_cast(bf16x8, f0);
    const bf16x8 pa1 = __builtin_bit_cast(bf16x8, f1);
    const bf16x8 pa2 = __builtin_bit_cast(bf16x8, f2);
    const bf16x8 pa3 = __builtin_bit_cast(bf16x8, f3);

#pragma unroll
    for (int ks = 0; ks < 4; ++ks) {
      if (!(skipHi && ks >= 2)) {
        const bf16x8 pa = (ks == 0) ? pa0 : (ks == 1) ? pa1 : (ks == 2) ? pa2 : pa3;
        const bf16x8 va0 = *reinterpret_cast<const bf16x8*>(&Vt[l31][ks * 16 + hi2 * 8]);
        const bf16x8 va1 = *reinterpret_cast<const bf16x8*>(&Vt[32 + l31][ks * 16 + hi2 * 8]);
        y0 = __builtin_amdgcn_mfma_f32_32x32x16_bf16(va0, pa, y0, 0, 0, 0);
        y1 = __builtin_amdgcn_mfma_f32_32x32x16_bf16(va1, pa, y1, 0, 0, 0);
      }
    }
  };

  for (int tt = w; tt < NT; tt += 4) {
    stageV(tt);
    bf16x8 kr[8];
    {
      const bf16* kp = K + (rb + tt * 64 + l31) * 1024 + hcol + hi2 * 8;
      const bf16* kp2 = kp + (size_t)32 * 1024;
#pragma unroll
      for (int i = 0; i < 4; ++i) {
        kr[i] = *reinterpret_cast<const bf16x8*>(kp + i * 16);
        kr[4 + i] = *reinterpret_cast<const bf16x8*>(kp2 + i * 16);
      }
    }

#pragma unroll
    for (int s = 0; s < 4; ++s) {
      const int dt = 2 * g + (s >> 1);
      if (tt > dt) continue;  // set fully masked for this tile (uniform)
      const bool diagLow = (tt == dt) && ((s & 1) == 0);
      const bool diagHi = (tt == dt) && ((s & 1) == 1);

      bf16x8 qf[4];
      {
        const bf16* qp = qp0 + (size_t)s * 32 * 1024;
#pragma unroll
        for (int kt = 0; kt < 4; ++kt)
          qf[kt] = *reinterpret_cast<const bf16x8*>(qp + kt * 16);
      }

      f32x16 s0 = {};
      s0 = __builtin_amdgcn_mfma_f32_32x32x16_bf16(kr[0], qf[0], s0, 0, 0, 0);
      s0 = __builtin_amdgcn_mfma_f32_32x32x16_bf16(kr[1], qf[1], s0, 0, 0, 0);
      s0 = __builtin_amdgcn_mfma_f32_32x32x16_bf16(kr[2], qf[2], s0, 0, 0, 0);
      s0 = __builtin_amdgcn_mfma_f32_32x32x16_bf16(kr[3], qf[3], s0, 0, 0, 0);
      f32x16 s1;
      if (!diagLow) {
        f32x16 t0 = {};
        t0 = __builtin_amdgcn_mfma_f32_32x32x16_bf16(kr[4], qf[0], t0, 0, 0, 0);
        t0 = __builtin_amdgcn_mfma_f32_32x32x16_bf16(kr[5], qf[1], t0, 0, 0, 0);
        t0 = __builtin_amdgcn_mfma_f32_32x32x16_bf16(kr[6], qf[2], t0, 0, 0, 0);
        t0 = __builtin_amdgcn_mfma_f32_32x32x16_bf16(kr[7], qf[3], t0, 0, 0, 0);
        s1 = t0;
      } else {
#pragma unroll
        for (int r = 0; r < 16; ++r) s1[r] = -INFINITY;  // high half all-masked
      }

      if (diagLow) {
#pragma unroll
        for (int r = 0; r < 16; ++r) {
          const int kvl = (r & 3) + 8 * (r >> 2) + 4 * hi2;
          if (kvl > l31) s0[r] = -INFINITY;
        }
      }
      if (diagHi) {
#pragma unroll
        for (int r = 0; r < 16; ++r) {
          const int kvl = (r & 3) + 8 * (r >> 2) + 4 * hi2;
          if (kvl > l31) s1[r] = -INFINITY;
        }
      }

      smax_pv64(s0, s1, m[s], l[s], y[s][0], y[s][1], diagLow);
    }
  }

  // ---- combine 4 wave-partials: 8 quarter-phases (set x d-half) ----
  __syncthreads();  // Vt dead; comb may alias it
  if (lane < 32) {
#pragma unroll
    for (int s = 0; s < 4; ++s) {
      mlS[w][0][s * 32 + l31] = m[s];
      mlS[w][1][s * 32 + l31] = l[s];
    }
  }

  auto comb_phase = [&](const f32x16& yy, int qoff, int dcol) {
#pragma unroll
    for (int r = 0; r < 16; r += 2) {
      const int d0 = (r & 3) + 8 * (r >> 2) + 4 * hi2;
      float2 v2;
      v2.x = yy[r];
      v2.y = yy[r + 1];
      *reinterpret_cast<float2*>(&combf[((size_t)w * 32 + l31) * 34 + d0]) = v2;
    }
    __syncthreads();

    const int tq = tid >> 3;       // 0..31 (q row within set)
    const int dg = (tid & 7) * 4;  // 0..28 (d offset within half)
    float mw[4], lw[4];
#pragma unroll
    for (int ww = 0; ww < 4; ++ww) {
      mw[ww] = mlS[ww][0][qoff + tq];
      lw[ww] = mlS[ww][1][qoff + tq];
    }
    const float M = fmaxf(fmaxf(mw[0], mw[1]), fmaxf(mw[2], mw[3]));
    float wg[4];
    float Lsum = 0.f;
#pragma unroll
    for (int ww = 0; ww < 4; ++ww) {
      wg[ww] = fexp2((mw[ww] - M) * cl2);
      Lsum += lw[ww] * wg[ww];
    }
    const float inv = 1.f / Lsum;
    float a4[4] = {};
#pragma unroll
    for (int ww = 0; ww < 4; ++ww)
#pragma unroll
      for (int jj = 0; jj < 4; ++jj)
        a4[jj] += wg[ww] * combf[((size_t)ww * 32 + tq) * 34 + dg + jj];
    bf16x4 o;
#pragma unroll
    for (int jj = 0; jj < 4; ++jj) o[jj] = (bf16)(a4[jj] * inv);
    *reinterpret_cast<bf16x4*>(Y + (rb + qbase + qoff + tq) * 1024 + hcol + dcol + dg) = o;
    __syncthreads();
  };

#pragma unroll
  for (int s = 0; s < 4; ++s) {
    comb_phase(y[s][0], s * 32, 0);
    comb_phase(y[s][1], s * 32, 32);
  }
}

// ---------------- host launch ----------------------------------------------
extern "C" void kernel_launch(void* const* d_in, const int* in_sizes, int n_in,
                              void* d_out, int out_size, void* d_ws,
                              size_t ws_size, hipStream_t stream) {
  const float* x = (const float*)d_in[0];
  const float* Wq = (const float*)d_in[1];
  const float* bq = (const float*)d_in[2];
  const float* Wk = (const float*)d_in[3];
  const float* bk = (const float*)d_in[4];
  const float* Wv = (const float*)d_in[5];
  const float* bv = (const float*)d_in[6];
  const float* Wp = (const float*)d_in[7];
  const float* bp = (const float*)d_in[8];

  const int BS = 4096;
  const int Dm = 1024;

  char* ws = (char*)d_ws;
  bf16* xb = (bf16*)(ws);
  bf16* wqb = (bf16*)(ws + (size_t)(8 << 20));
  bf16* wkb = (bf16*)(ws + (size_t)(10 << 20));
  bf16* wvb = (bf16*)(ws + (size_t)(12 << 20));
  bf16* wpb = (bf16*)(ws + (size_t)(14 << 20));
  bf16* Qb = (bf16*)(ws + (size_t)(16 << 20));
  bf16* Kb = (bf16*)(ws + (size_t)(24 << 20));
  bf16* Vb = (bf16*)(ws + (size_t)(32 << 20));
  bf16* Yb = (bf16*)(ws + (size_t)(40 << 20));

  CvtArgs ca;
  ca.src[0] = x;  ca.dst[0] = xb;  ca.n[0] = BS * Dm;
  ca.src[1] = Wq; ca.dst[1] = wqb; ca.n[1] = Dm * Dm;
  ca.src[2] = Wk; ca.dst[2] = wkb; ca.n[2] = Dm * Dm;
  ca.src[3] = Wv; ca.dst[3] = wvb; ca.n[3] = Dm * Dm;
  ca.src[4] = Wp; ca.dst[4] = wpb; ca.n[4] = Dm * Dm;
  cvt_multi<<<dim3(1024, 5), 256, 0, stream>>>(ca);

  GemmBatch gq;
  gq.Bw[0] = wqb; gq.bias[0] = bq; gq.C[0] = Qb;
  gq.Bw[1] = wkb; gq.bias[1] = bk; gq.C[1] = Kb;
  gq.Bw[2] = wvb; gq.bias[2] = bv; gq.C[2] = Vb;
  gemm128<true><<<dim3(32, 8, 3), 256, 0, stream>>>(xb, gq, BS, Dm, Dm);

  attn_ws<<<dim3(512), 256, 0, stream>>>(Qb, Kb, Vb, Yb);

  GemmBatch gp;
  gp.Bw[0] = wpb; gp.bias[0] = bp; gp.C[0] = d_out;
  gp.Bw[1] = wpb; gp.bias[1] = bp; gp.C[1] = d_out;
  gp.Bw[2] = wpb; gp.bias[2] = bp; gp.C[2] = d_out;
  gemm128<false><<<dim3(32, 8, 1), 256, 0, stream>>>(Yb, gp, BS, Dm, Dm);
}

// Round 22
// 123.732 us; speedup vs baseline: 1.0891x; 1.0891x over previous
//
#include <hip/hip_runtime.h>
#include <hip/hip_bf16.h>

typedef __bf16 bf16;
typedef bf16 bf16x4 __attribute__((ext_vector_type(4)));
typedef bf16 bf16x8 __attribute__((ext_vector_type(8)));
typedef float f32x4 __attribute__((ext_vector_type(4)));
typedef float f32x16 __attribute__((ext_vector_type(16)));
typedef unsigned int u32x4 __attribute__((ext_vector_type(4)));

#define LOG2E 1.44269504088896340736f

__device__ __forceinline__ void gload_lds16(const bf16* g, bf16* l) {
  __builtin_amdgcn_global_load_lds(
      (const __attribute__((address_space(1))) void*)g,
      (__attribute__((address_space(3))) void*)l, 16, 0, 0);
}

// raw v_exp_f32 (2^x): args here are always <= ~8, -inf ok (-> 0)
__device__ __forceinline__ float fexp2(float x) {
  float r;
  asm("v_exp_f32 %0, %1" : "=v"(r) : "v"(x));
  return r;
}

// ---------------- fp32 -> bf16 conversion (5 segments in one launch) -------
struct CvtArgs {
  const float* src[5];
  bf16* dst[5];
  int n[5];
};

__global__ __launch_bounds__(256) void cvt_multi(CvtArgs a) {
  const int seg = blockIdx.y;
  const float* __restrict__ s = a.src[seg];
  bf16* __restrict__ d = a.dst[seg];
  const int n = a.n[seg];
  int i = (blockIdx.x * 256 + threadIdx.x) * 4;
  const int stride = gridDim.x * 256 * 4;
  for (; i < n; i += stride) {
    float4 f = *reinterpret_cast<const float4*>(s + i);
    bf16x4 o = {(bf16)f.x, (bf16)f.y, (bf16)f.z, (bf16)f.w};
    *reinterpret_cast<bf16x4*>(d + i) = o;
  }
}

// ---------------- 128x128 bf16 GEMM (BK=64), C = A * B^T + bias ------------
// BK=64 (r18: -4us vs BK=32 -- halves per-iteration vmcnt(0)+barrier drains).
// Future work: 256^2 8-phase template (counted vmcnt(6), st_16x32 swizzle)
// needs disasm-in-loop to land.
struct GemmBatch {
  const bf16* Bw[3];
  const float* bias[3];
  void* C[3];
};

template <bool OUT_BF16>
__global__ __launch_bounds__(256, 2) void gemm128(const bf16* __restrict__ A,
                                                  GemmBatch gb, int M, int N,
                                                  int K) {
  const int tid = threadIdx.x;
  const int wid = tid >> 6;
  const int lane = tid & 63;
  const int l16 = lane & 15;
  const int hi = lane >> 4;
  const int m0 = blockIdx.x * 128;
  const int n0 = blockIdx.y * 128;
  const int z = blockIdx.z;
  const bf16* __restrict__ Bw = gb.Bw[z];
  const float* __restrict__ bias = gb.bias[z];

  __shared__ bf16 As[128 * 64];
  __shared__ bf16 Bs[128 * 64];

  f32x4 acc[4][4] = {};

  const int wm = (wid >> 1) * 64;
  const int wn = (wid & 1) * 64;

  for (int k0 = 0; k0 < K; k0 += 64) {
#pragma unroll
    for (int i = 0; i < 4; ++i) {
      const int chunk = wid + 4 * i;               // 0..15, wave-uniform
      const int p = chunk * 1024 + lane * 16;      // physical LDS byte
      const int row = p >> 7;                      // 128B per row (64 bf16)
      const int cb = (p & 112) ^ ((row & 3) << 4); // logical col byte
      gload_lds16(A + (size_t)(m0 + row) * K + k0 + (cb >> 1), As + chunk * 512);
      gload_lds16(Bw + (size_t)(n0 + row) * K + k0 + (cb >> 1), Bs + chunk * 512);
    }
    __syncthreads();

#pragma unroll
    for (int ks = 0; ks < 2; ++ks) {
      bf16x8 af[4], bfr[4];
#pragma unroll
      for (int m = 0; m < 4; ++m) {
        const int r = wm + m * 16 + l16;
        const int pb = r * 128 + ((ks * 64 + hi * 16) ^ ((r & 3) << 4));
        af[m] = *reinterpret_cast<const bf16x8*>((const char*)As + pb);
      }
#pragma unroll
      for (int n = 0; n < 4; ++n) {
        const int r = wn + n * 16 + l16;
        const int pb = r * 128 + ((ks * 64 + hi * 16) ^ ((r & 3) << 4));
        bfr[n] = *reinterpret_cast<const bf16x8*>((const char*)Bs + pb);
      }
#pragma unroll
      for (int m = 0; m < 4; ++m)
#pragma unroll
        for (int n = 0; n < 4; ++n)
          acc[m][n] =
              __builtin_amdgcn_mfma_f32_16x16x32_bf16(af[m], bfr[n], acc[m][n], 0, 0, 0);
    }
    __syncthreads();
  }

  const int rbase = m0 + wm + hi * 4;
  const int cbase = n0 + wn + l16;
#pragma unroll
  for (int n = 0; n < 4; ++n) {
    const int col = cbase + n * 16;
    const float bv = bias[col];
#pragma unroll
    for (int m = 0; m < 4; ++m) {
#pragma unroll
      for (int j = 0; j < 4; ++j) {
        const int row = rbase + m * 16 + j;
        const float v = acc[m][n][j] + bv;
        if (OUT_BF16)
          ((bf16*)gb.C[z])[(size_t)row * N + col] = (bf16)v;
        else
          ((float*)gb.C[z])[(size_t)row * N + col] = v;
      }
    }
  }
}

// ---------------- causal flash attention, wave-split KV, 64q x 64kv --------
// BEST MEASURED (r18/r20: attn 66.5us, total 123.6-123.8us, reproduced 2x).
// 512 paired blocks x 256 threads; uniform 33 KV64-tiles/block; TWO 32x32x64
// score sets per tile sharing K frags and one Vt[64][72] staging; batched
// softmax per 64 kv; shfl-only cross-half reduces.
// Session lessons (falsified levers -- do not retry without disasm):
//  - r7: launch_bounds min-waves must never cap VGPR below live set (spills).
//  - r9/r11/r12: compiler sinks reg prefetch loads; sched_barrier and
//    asm-volatile prefetch don't fix it (neutral/negative).
//  - r10/r14: permlane32_swap copy-then-swap helper corrupts (banned);
//    the P-frag pair-swap usage is fine.
//  - r13: q-tile growth 32->64 rows/wave was the big win (+50%).
//  - r17: KVBLK 32->64 neutral (softmax overhead not the binder).
//  - r19: 8-wave/512-thread block regresses (DS contention + conflicts).
//  - r21: 4 q-sets/wave spills (WRITE +5MB, VGPR capped 128) -> 2 sets max.
__global__ __launch_bounds__(256, 2) void attn_ws(const bf16* __restrict__ Q,
                                                  const bf16* __restrict__ K,
                                                  const bf16* __restrict__ V,
                                                  bf16* __restrict__ Y) {
  const int p = blockIdx.x;    // 0..511
  const int bh = p & 31;       // XCD p%8 sees streams {bh : bh%8 == p%8}
  const int jp = p >> 5;       // 0..15
  const int h = bh & 15;
  const int b = bh >> 4;

  const int tid = threadIdx.x;
  const int w = tid >> 6;
  const int lane = tid & 63;
  const int l31 = lane & 31;
  const int hi2 = lane >> 5;
  const size_t rb = (size_t)b * 2048;
  const int hcol = h * 64;
  const float cl2 = 0.125f * LOG2E;

  __shared__ char smem[36864];
  __shared__ float mlS[4][2][64];
  bf16(*Vt)[72] = (bf16(*)[72])(smem + (size_t)w * 9216);
  float* combf = (float*)smem;

  const int kvg = lane & 7;   // staging: kv quad group
  const int dgr = lane >> 3;  // staging: d quad group (0..7)

  auto stageV = [&](int tt) {
    const bf16* vp0 = V + (rb + tt * 64 + kvg * 4) * 1024 + hcol + dgr * 4;
#pragma unroll
    for (int hh = 0; hh < 2; ++hh) {
      const bf16* vp = vp0 + (size_t)hh * 32 * 1024;
      bf16x4 vr[2][4];
#pragma unroll
      for (int r = 0; r < 2; ++r)
#pragma unroll
        for (int jj = 0; jj < 4; ++jj)
          vr[r][jj] = *reinterpret_cast<const bf16x4*>(vp + (size_t)jj * 1024 + r * 32);
#pragma unroll
      for (int r = 0; r < 2; ++r)
#pragma unroll
        for (int kc = 0; kc < 4; ++kc) {
          bf16x4 wv = {vr[r][0][kc], vr[r][1][kc], vr[r][2][kc], vr[r][3][kc]};
          *reinterpret_cast<bf16x4*>(&Vt[r * 32 + dgr * 4 + kc][hh * 32 + kvg * 4]) = wv;
        }
    }
  };

  auto run = [&](int qg) {
    const int qbase = qg * 64;
    const int NT = qg + 1;  // kv tiles of 64

    bf16x8 qfA[4], qfB[4];
    {
      const bf16* qpA = Q + (rb + qbase + l31) * 1024 + hcol + hi2 * 8;
      const bf16* qpB = qpA + (size_t)32 * 1024;
#pragma unroll
      for (int kt = 0; kt < 4; ++kt) {
        qfA[kt] = *reinterpret_cast<const bf16x8*>(qpA + kt * 16);
        qfB[kt] = *reinterpret_cast<const bf16x8*>(qpB + kt * 16);
      }
    }

    f32x16 yA0 = {}, yA1 = {}, yB0 = {}, yB1 = {};
    float mA = -INFINITY, lA = 0.f, mB = -INFINITY, lB = 0.f;

    auto smax_pv64 = [&](f32x16& s0, f32x16& s1, float& m, float& l,
                         f32x16& y0, f32x16& y1, bool skipHi) {
      float red[8];
#pragma unroll
      for (int i = 0; i < 8; ++i)
        red[i] = fmaxf(fmaxf(s0[i], s0[i + 8]), fmaxf(s1[i], s1[i + 8]));
#pragma unroll
      for (int i = 0; i < 4; ++i) red[i] = fmaxf(red[i], red[i + 4]);
      float pm = fmaxf(fmaxf(red[0], red[1]), fmaxf(red[2], red[3]));
      pm = fmaxf(pm, __shfl_xor(pm, 32));

      if (!__all(pm <= m + 40.f)) {  // defer-max (T13)
        const float mn = fmaxf(m, pm);
        const float al = fexp2((m - mn) * cl2);
#pragma unroll
        for (int r = 0; r < 16; ++r) {
          y0[r] *= al;
          y1[r] *= al;
        }
        l *= al;
        m = mn;
      }
      const float mc = m * cl2;
      float ps[32];
#pragma unroll
      for (int r = 0; r < 16; ++r) ps[r] = fexp2(s0[r] * cl2 - mc);
#pragma unroll
      for (int r = 0; r < 16; ++r) ps[16 + r] = fexp2(s1[r] * cl2 - mc);
      float sum[16];
#pragma unroll
      for (int i = 0; i < 16; ++i) sum[i] = ps[i] + ps[i + 16];
#pragma unroll
      for (int i = 0; i < 8; ++i) sum[i] += sum[i + 8];
#pragma unroll
      for (int i = 0; i < 4; ++i) sum[i] += sum[i + 4];
      float rs = (sum[0] + sum[1]) + (sum[2] + sum[3]);
      rs += __shfl_xor(rs, 32);
      l += rs;

      unsigned int pk[16];
#pragma unroll
      for (int i = 0; i < 16; ++i) {
        const unsigned short a = __builtin_bit_cast(unsigned short, (bf16)ps[2 * i]);
        const unsigned short c = __builtin_bit_cast(unsigned short, (bf16)ps[2 * i + 1]);
        pk[i] = (unsigned int)a | ((unsigned int)c << 16);
      }
      asm("v_permlane32_swap_b32 %0, %1" : "+v"(pk[0]), "+v"(pk[2]));
      asm("v_permlane32_swap_b32 %0, %1" : "+v"(pk[1]), "+v"(pk[3]));
      asm("v_permlane32_swap_b32 %0, %1" : "+v"(pk[4]), "+v"(pk[6]));
      asm("v_permlane32_swap_b32 %0, %1" : "+v"(pk[5]), "+v"(pk[7]));
      asm("v_permlane32_swap_b32 %0, %1" : "+v"(pk[8]), "+v"(pk[10]));
      asm("v_permlane32_swap_b32 %0, %1" : "+v"(pk[9]), "+v"(pk[11]));
      asm("v_permlane32_swap_b32 %0, %1" : "+v"(pk[12]), "+v"(pk[14]));
      asm("v_permlane32_swap_b32 %0, %1" : "+v"(pk[13]), "+v"(pk[15]));
      const u32x4 f0 = {pk[0], pk[1], pk[2], pk[3]};
      const u32x4 f1 = {pk[4], pk[5], pk[6], pk[7]};
      const u32x4 f2 = {pk[8], pk[9], pk[10], pk[11]};
      const u32x4 f3 = {pk[12], pk[13], pk[14], pk[15]};
      const bf16x8 pa0 = __builtin_bit_cast(bf16x8, f0);
      const bf16x8 pa1 = __builtin_bit_cast(bf16x8, f1);
      const bf16x8 pa2 = __builtin_bit_cast(bf16x8, f2);
      const bf16x8 pa3 = __builtin_bit_cast(bf16x8, f3);

#pragma unroll
      for (int ks = 0; ks < 4; ++ks) {
        if (!(skipHi && ks >= 2)) {
          const bf16x8 pa = (ks == 0) ? pa0 : (ks == 1) ? pa1 : (ks == 2) ? pa2 : pa3;
          const bf16x8 va0 = *reinterpret_cast<const bf16x8*>(&Vt[l31][ks * 16 + hi2 * 8]);
          const bf16x8 va1 = *reinterpret_cast<const bf16x8*>(&Vt[32 + l31][ks * 16 + hi2 * 8]);
          y0 = __builtin_amdgcn_mfma_f32_32x32x16_bf16(va0, pa, y0, 0, 0, 0);
          y1 = __builtin_amdgcn_mfma_f32_32x32x16_bf16(va1, pa, y1, 0, 0, 0);
        }
      }
    };

    for (int tt = w; tt < NT; tt += 4) {
      stageV(tt);
      bf16x8 kr[8];
      {
        const bf16* kp = K + (rb + tt * 64 + l31) * 1024 + hcol + hi2 * 8;
        const bf16* kp2 = kp + (size_t)32 * 1024;
#pragma unroll
        for (int i = 0; i < 4; ++i) {
          kr[i] = *reinterpret_cast<const bf16x8*>(kp + i * 16);
          kr[4 + i] = *reinterpret_cast<const bf16x8*>(kp2 + i * 16);
        }
      }
      const bool diag = (tt == qg);

      f32x16 sA0 = {}, sA1, sB0 = {}, sB1 = {};
      sA0 = __builtin_amdgcn_mfma_f32_32x32x16_bf16(kr[0], qfA[0], sA0, 0, 0, 0);
      sA0 = __builtin_amdgcn_mfma_f32_32x32x16_bf16(kr[1], qfA[1], sA0, 0, 0, 0);
      sA0 = __builtin_amdgcn_mfma_f32_32x32x16_bf16(kr[2], qfA[2], sA0, 0, 0, 0);
      sA0 = __builtin_amdgcn_mfma_f32_32x32x16_bf16(kr[3], qfA[3], sA0, 0, 0, 0);
      if (!diag) {
        f32x16 t0 = {};
        t0 = __builtin_amdgcn_mfma_f32_32x32x16_bf16(kr[4], qfA[0], t0, 0, 0, 0);
        t0 = __builtin_amdgcn_mfma_f32_32x32x16_bf16(kr[5], qfA[1], t0, 0, 0, 0);
        t0 = __builtin_amdgcn_mfma_f32_32x32x16_bf16(kr[6], qfA[2], t0, 0, 0, 0);
        t0 = __builtin_amdgcn_mfma_f32_32x32x16_bf16(kr[7], qfA[3], t0, 0, 0, 0);
        sA1 = t0;
      } else {
#pragma unroll
        for (int r = 0; r < 16; ++r) sA1[r] = -INFINITY;  // kv-high > all A rows
      }
      sB0 = __builtin_amdgcn_mfma_f32_32x32x16_bf16(kr[0], qfB[0], sB0, 0, 0, 0);
      sB0 = __builtin_amdgcn_mfma_f32_32x32x16_bf16(kr[1], qfB[1], sB0, 0, 0, 0);
      sB0 = __builtin_amdgcn_mfma_f32_32x32x16_bf16(kr[2], qfB[2], sB0, 0, 0, 0);
      sB0 = __builtin_amdgcn_mfma_f32_32x32x16_bf16(kr[3], qfB[3], sB0, 0, 0, 0);
      sB1 = __builtin_amdgcn_mfma_f32_32x32x16_bf16(kr[4], qfB[0], sB1, 0, 0, 0);
      sB1 = __builtin_amdgcn_mfma_f32_32x32x16_bf16(kr[5], qfB[1], sB1, 0, 0, 0);
      sB1 = __builtin_amdgcn_mfma_f32_32x32x16_bf16(kr[6], qfB[2], sB1, 0, 0, 0);
      sB1 = __builtin_amdgcn_mfma_f32_32x32x16_bf16(kr[7], qfB[3], sB1, 0, 0, 0);

      if (diag) {
#pragma unroll
        for (int r = 0; r < 16; ++r) {
          const int kvl = (r & 3) + 8 * (r >> 2) + 4 * hi2;
          if (kvl > l31) sA0[r] = -INFINITY;  // A diag in kv-low
          if (kvl > l31) sB1[r] = -INFINITY;  // B diag in kv-high
        }
      }

      smax_pv64(sA0, sA1, mA, lA, yA0, yA1, diag);
      smax_pv64(sB0, sB1, mB, lB, yB0, yB1, false);
    }

    // ---- combine 4 wave-partials: 4 quarter-phases (A/B x d-half) ----
    __syncthreads();  // Vt dead; comb may alias it
    if (lane < 32) {
      mlS[w][0][l31] = mA;
      mlS[w][1][l31] = lA;
      mlS[w][0][32 + l31] = mB;
      mlS[w][1][32 + l31] = lB;
    }

    auto comb_phase = [&](const f32x16& y, int qoff, int dcol) {
#pragma unroll
      for (int r = 0; r < 16; r += 2) {
        const int d0 = (r & 3) + 8 * (r >> 2) + 4 * hi2;
        float2 v2;
        v2.x = y[r];
        v2.y = y[r + 1];
        *reinterpret_cast<float2*>(&combf[((size_t)w * 32 + l31) * 34 + d0]) = v2;
      }
      __syncthreads();

      const int tq = tid >> 3;       // 0..31 (q row within set)
      const int dg = (tid & 7) * 4;  // 0..28 (d offset within half)
      float mw[4], lw[4];
#pragma unroll
      for (int ww = 0; ww < 4; ++ww) {
        mw[ww] = mlS[ww][0][qoff + tq];
        lw[ww] = mlS[ww][1][qoff + tq];
      }
      const float M = fmaxf(fmaxf(mw[0], mw[1]), fmaxf(mw[2], mw[3]));
      float wg[4];
      float Lsum = 0.f;
#pragma unroll
      for (int ww = 0; ww < 4; ++ww) {
        wg[ww] = fexp2((mw[ww] - M) * cl2);
        Lsum += lw[ww] * wg[ww];
      }
      const float inv = 1.f / Lsum;
      float a4[4] = {};
#pragma unroll
      for (int ww = 0; ww < 4; ++ww)
#pragma unroll
        for (int jj = 0; jj < 4; ++jj)
          a4[jj] += wg[ww] * combf[((size_t)ww * 32 + tq) * 34 + dg + jj];
      bf16x4 o;
#pragma unroll
      for (int jj = 0; jj < 4; ++jj) o[jj] = (bf16)(a4[jj] * inv);
      *reinterpret_cast<bf16x4*>(Y + (rb + qbase + qoff + tq) * 1024 + hcol + dcol + dg) = o;
      __syncthreads();
    };

    comb_phase(yA0, 0, 0);
    comb_phase(yA1, 0, 32);
    comb_phase(yB0, 32, 0);
    comb_phase(yB1, 32, 32);
  };

  run(31 - jp);
  run(jp);
}

// ---------------- host launch ----------------------------------------------
extern "C" void kernel_launch(void* const* d_in, const int* in_sizes, int n_in,
                              void* d_out, int out_size, void* d_ws,
                              size_t ws_size, hipStream_t stream) {
  const float* x = (const float*)d_in[0];
  const float* Wq = (const float*)d_in[1];
  const float* bq = (const float*)d_in[2];
  const float* Wk = (const float*)d_in[3];
  const float* bk = (const float*)d_in[4];
  const float* Wv = (const float*)d_in[5];
  const float* bv = (const float*)d_in[6];
  const float* Wp = (const float*)d_in[7];
  const float* bp = (const float*)d_in[8];

  const int BS = 4096;
  const int Dm = 1024;

  char* ws = (char*)d_ws;
  bf16* xb = (bf16*)(ws);
  bf16* wqb = (bf16*)(ws + (size_t)(8 << 20));
  bf16* wkb = (bf16*)(ws + (size_t)(10 << 20));
  bf16* wvb = (bf16*)(ws + (size_t)(12 << 20));
  bf16* wpb = (bf16*)(ws + (size_t)(14 << 20));
  bf16* Qb = (bf16*)(ws + (size_t)(16 << 20));
  bf16* Kb = (bf16*)(ws + (size_t)(24 << 20));
  bf16* Vb = (bf16*)(ws + (size_t)(32 << 20));
  bf16* Yb = (bf16*)(ws + (size_t)(40 << 20));

  CvtArgs ca;
  ca.src[0] = x;  ca.dst[0] = xb;  ca.n[0] = BS * Dm;
  ca.src[1] = Wq; ca.dst[1] = wqb; ca.n[1] = Dm * Dm;
  ca.src[2] = Wk; ca.dst[2] = wkb; ca.n[2] = Dm * Dm;
  ca.src[3] = Wv; ca.dst[3] = wvb; ca.n[3] = Dm * Dm;
  ca.src[4] = Wp; ca.dst[4] = wpb; ca.n[4] = Dm * Dm;
  cvt_multi<<<dim3(1024, 5), 256, 0, stream>>>(ca);

  GemmBatch gq;
  gq.Bw[0] = wqb; gq.bias[0] = bq; gq.C[0] = Qb;
  gq.Bw[1] = wkb; gq.bias[1] = bk; gq.C[1] = Kb;
  gq.Bw[2] = wvb; gq.bias[2] = bv; gq.C[2] = Vb;
  gemm128<true><<<dim3(32, 8, 3), 256, 0, stream>>>(xb, gq, BS, Dm, Dm);

  attn_ws<<<dim3(512), 256, 0, stream>>>(Qb, Kb, Vb, Yb);

  GemmBatch gp;
  gp.Bw[0] = wpb; gp.bias[0] = bp; gp.C[0] = d_out;
  gp.Bw[1] = wpb; gp.bias[1] = bp; gp.C[1] = d_out;
  gp.Bw[2] = wpb; gp.bias[2] = bp; gp.C[2] = d_out;
  gemm128<false><<<dim3(32, 8, 1), 256, 0, stream>>>(Yb, gp, BS, Dm, Dm);
}

// Round 23
// 122.143 us; speedup vs baseline: 1.1032x; 1.0130x over previous
//
#include <hip/hip_runtime.h>
#include <hip/hip_bf16.h>

typedef __bf16 bf16;
typedef bf16 bf16x4 __attribute__((ext_vector_type(4)));
typedef bf16 bf16x8 __attribute__((ext_vector_type(8)));
typedef float f32x4 __attribute__((ext_vector_type(4)));
typedef float f32x16 __attribute__((ext_vector_type(16)));
typedef unsigned int u32x4 __attribute__((ext_vector_type(4)));

#define LOG2E 1.44269504088896340736f

__device__ __forceinline__ void gload_lds16(const bf16* g, bf16* l) {
  __builtin_amdgcn_global_load_lds(
      (const __attribute__((address_space(1))) void*)g,
      (__attribute__((address_space(3))) void*)l, 16, 0, 0);
}

// raw v_exp_f32 (2^x): args here are always <= ~8, -inf ok (-> 0)
__device__ __forceinline__ float fexp2(float x) {
  float r;
  asm("v_exp_f32 %0, %1" : "=v"(r) : "v"(x));
  return r;
}

// ---------------- fp32 -> bf16 conversion (5 segments in one launch) -------
struct CvtArgs {
  const float* src[5];
  bf16* dst[5];
  int n[5];
};

__global__ __launch_bounds__(256) void cvt_multi(CvtArgs a) {
  const int seg = blockIdx.y;
  const float* __restrict__ s = a.src[seg];
  bf16* __restrict__ d = a.dst[seg];
  const int n = a.n[seg];
  int i = (blockIdx.x * 256 + threadIdx.x) * 4;
  const int stride = gridDim.x * 256 * 4;
  for (; i < n; i += stride) {
    float4 f = *reinterpret_cast<const float4*>(s + i);
    bf16x4 o = {(bf16)f.x, (bf16)f.y, (bf16)f.z, (bf16)f.w};
    *reinterpret_cast<bf16x4*>(d + i) = o;
  }
}

// ---------------- 128x128 bf16 GEMM (BK=64), C = A * B^T + bias ------------
// BK=64 (r18: -4us vs BK=32 -- halves per-iteration vmcnt(0)+barrier drains).
struct GemmBatch {
  const bf16* Bw[3];
  const float* bias[3];
  void* C[3];
};

template <bool OUT_BF16>
__global__ __launch_bounds__(256, 2) void gemm128(const bf16* __restrict__ A,
                                                  GemmBatch gb, int M, int N,
                                                  int K) {
  const int tid = threadIdx.x;
  const int wid = tid >> 6;
  const int lane = tid & 63;
  const int l16 = lane & 15;
  const int hi = lane >> 4;
  const int m0 = blockIdx.x * 128;
  const int n0 = blockIdx.y * 128;
  const int z = blockIdx.z;
  const bf16* __restrict__ Bw = gb.Bw[z];
  const float* __restrict__ bias = gb.bias[z];

  __shared__ bf16 As[128 * 64];
  __shared__ bf16 Bs[128 * 64];

  f32x4 acc[4][4] = {};

  const int wm = (wid >> 1) * 64;
  const int wn = (wid & 1) * 64;

  for (int k0 = 0; k0 < K; k0 += 64) {
#pragma unroll
    for (int i = 0; i < 4; ++i) {
      const int chunk = wid + 4 * i;               // 0..15, wave-uniform
      const int p = chunk * 1024 + lane * 16;      // physical LDS byte
      const int row = p >> 7;                      // 128B per row (64 bf16)
      const int cb = (p & 112) ^ ((row & 3) << 4); // logical col byte
      gload_lds16(A + (size_t)(m0 + row) * K + k0 + (cb >> 1), As + chunk * 512);
      gload_lds16(Bw + (size_t)(n0 + row) * K + k0 + (cb >> 1), Bs + chunk * 512);
    }
    __syncthreads();

#pragma unroll
    for (int ks = 0; ks < 2; ++ks) {
      bf16x8 af[4], bfr[4];
#pragma unroll
      for (int m = 0; m < 4; ++m) {
        const int r = wm + m * 16 + l16;
        const int pb = r * 128 + ((ks * 64 + hi * 16) ^ ((r & 3) << 4));
        af[m] = *reinterpret_cast<const bf16x8*>((const char*)As + pb);
      }
#pragma unroll
      for (int n = 0; n < 4; ++n) {
        const int r = wn + n * 16 + l16;
        const int pb = r * 128 + ((ks * 64 + hi * 16) ^ ((r & 3) << 4));
        bfr[n] = *reinterpret_cast<const bf16x8*>((const char*)Bs + pb);
      }
#pragma unroll
      for (int m = 0; m < 4; ++m)
#pragma unroll
        for (int n = 0; n < 4; ++n)
          acc[m][n] =
              __builtin_amdgcn_mfma_f32_16x16x32_bf16(af[m], bfr[n], acc[m][n], 0, 0, 0);
    }
    __syncthreads();
  }

  const int rbase = m0 + wm + hi * 4;
  const int cbase = n0 + wn + l16;
#pragma unroll
  for (int n = 0; n < 4; ++n) {
    const int col = cbase + n * 16;
    const float bv = bias[col];
#pragma unroll
    for (int m = 0; m < 4; ++m) {
#pragma unroll
      for (int j = 0; j < 4; ++j) {
        const int row = rbase + m * 16 + j;
        const float v = acc[m][n][j] + bv;
        if (OUT_BF16)
          ((bf16*)gb.C[z])[(size_t)row * N + col] = (bf16)v;
        else
          ((float*)gb.C[z])[(size_t)row * N + col] = v;
      }
    }
  }
}

// ---------------- causal flash attention, wave-split KV, 64q x 64kv --------
// r23 = r20 (66.5us attn, 3x reproduced) + T5 s_setprio around MFMA clusters.
// T5 regime match (m191): independent waves at different phases (no main-loop
// barriers here) -> boosting priority during QK^T/PV clusters lets the CU
// scheduler prefer the MFMA-issuing wave while others issue loads/VALU.
// Single variable vs r20; revert if neutral/negative.
__global__ __launch_bounds__(256, 2) void attn_ws(const bf16* __restrict__ Q,
                                                  const bf16* __restrict__ K,
                                                  const bf16* __restrict__ V,
                                                  bf16* __restrict__ Y) {
  const int p = blockIdx.x;    // 0..511
  const int bh = p & 31;       // XCD p%8 sees streams {bh : bh%8 == p%8}
  const int jp = p >> 5;       // 0..15
  const int h = bh & 15;
  const int b = bh >> 4;

  const int tid = threadIdx.x;
  const int w = tid >> 6;
  const int lane = tid & 63;
  const int l31 = lane & 31;
  const int hi2 = lane >> 5;
  const size_t rb = (size_t)b * 2048;
  const int hcol = h * 64;
  const float cl2 = 0.125f * LOG2E;

  __shared__ char smem[36864];
  __shared__ float mlS[4][2][64];
  bf16(*Vt)[72] = (bf16(*)[72])(smem + (size_t)w * 9216);
  float* combf = (float*)smem;

  const int kvg = lane & 7;   // staging: kv quad group
  const int dgr = lane >> 3;  // staging: d quad group (0..7)

  auto stageV = [&](int tt) {
    const bf16* vp0 = V + (rb + tt * 64 + kvg * 4) * 1024 + hcol + dgr * 4;
#pragma unroll
    for (int hh = 0; hh < 2; ++hh) {
      const bf16* vp = vp0 + (size_t)hh * 32 * 1024;
      bf16x4 vr[2][4];
#pragma unroll
      for (int r = 0; r < 2; ++r)
#pragma unroll
        for (int jj = 0; jj < 4; ++jj)
          vr[r][jj] = *reinterpret_cast<const bf16x4*>(vp + (size_t)jj * 1024 + r * 32);
#pragma unroll
      for (int r = 0; r < 2; ++r)
#pragma unroll
        for (int kc = 0; kc < 4; ++kc) {
          bf16x4 wv = {vr[r][0][kc], vr[r][1][kc], vr[r][2][kc], vr[r][3][kc]};
          *reinterpret_cast<bf16x4*>(&Vt[r * 32 + dgr * 4 + kc][hh * 32 + kvg * 4]) = wv;
        }
    }
  };

  auto run = [&](int qg) {
    const int qbase = qg * 64;
    const int NT = qg + 1;  // kv tiles of 64

    bf16x8 qfA[4], qfB[4];
    {
      const bf16* qpA = Q + (rb + qbase + l31) * 1024 + hcol + hi2 * 8;
      const bf16* qpB = qpA + (size_t)32 * 1024;
#pragma unroll
      for (int kt = 0; kt < 4; ++kt) {
        qfA[kt] = *reinterpret_cast<const bf16x8*>(qpA + kt * 16);
        qfB[kt] = *reinterpret_cast<const bf16x8*>(qpB + kt * 16);
      }
    }

    f32x16 yA0 = {}, yA1 = {}, yB0 = {}, yB1 = {};
    float mA = -INFINITY, lA = 0.f, mB = -INFINITY, lB = 0.f;

    auto smax_pv64 = [&](f32x16& s0, f32x16& s1, float& m, float& l,
                         f32x16& y0, f32x16& y1, bool skipHi) {
      float red[8];
#pragma unroll
      for (int i = 0; i < 8; ++i)
        red[i] = fmaxf(fmaxf(s0[i], s0[i + 8]), fmaxf(s1[i], s1[i + 8]));
#pragma unroll
      for (int i = 0; i < 4; ++i) red[i] = fmaxf(red[i], red[i + 4]);
      float pm = fmaxf(fmaxf(red[0], red[1]), fmaxf(red[2], red[3]));
      pm = fmaxf(pm, __shfl_xor(pm, 32));

      if (!__all(pm <= m + 40.f)) {  // defer-max (T13)
        const float mn = fmaxf(m, pm);
        const float al = fexp2((m - mn) * cl2);
#pragma unroll
        for (int r = 0; r < 16; ++r) {
          y0[r] *= al;
          y1[r] *= al;
        }
        l *= al;
        m = mn;
      }
      const float mc = m * cl2;
      float ps[32];
#pragma unroll
      for (int r = 0; r < 16; ++r) ps[r] = fexp2(s0[r] * cl2 - mc);
#pragma unroll
      for (int r = 0; r < 16; ++r) ps[16 + r] = fexp2(s1[r] * cl2 - mc);
      float sum[16];
#pragma unroll
      for (int i = 0; i < 16; ++i) sum[i] = ps[i] + ps[i + 16];
#pragma unroll
      for (int i = 0; i < 8; ++i) sum[i] += sum[i + 8];
#pragma unroll
      for (int i = 0; i < 4; ++i) sum[i] += sum[i + 4];
      float rs = (sum[0] + sum[1]) + (sum[2] + sum[3]);
      rs += __shfl_xor(rs, 32);
      l += rs;

      unsigned int pk[16];
#pragma unroll
      for (int i = 0; i < 16; ++i) {
        const unsigned short a = __builtin_bit_cast(unsigned short, (bf16)ps[2 * i]);
        const unsigned short c = __builtin_bit_cast(unsigned short, (bf16)ps[2 * i + 1]);
        pk[i] = (unsigned int)a | ((unsigned int)c << 16);
      }
      asm("v_permlane32_swap_b32 %0, %1" : "+v"(pk[0]), "+v"(pk[2]));
      asm("v_permlane32_swap_b32 %0, %1" : "+v"(pk[1]), "+v"(pk[3]));
      asm("v_permlane32_swap_b32 %0, %1" : "+v"(pk[4]), "+v"(pk[6]));
      asm("v_permlane32_swap_b32 %0, %1" : "+v"(pk[5]), "+v"(pk[7]));
      asm("v_permlane32_swap_b32 %0, %1" : "+v"(pk[8]), "+v"(pk[10]));
      asm("v_permlane32_swap_b32 %0, %1" : "+v"(pk[9]), "+v"(pk[11]));
      asm("v_permlane32_swap_b32 %0, %1" : "+v"(pk[12]), "+v"(pk[14]));
      asm("v_permlane32_swap_b32 %0, %1" : "+v"(pk[13]), "+v"(pk[15]));
      const u32x4 f0 = {pk[0], pk[1], pk[2], pk[3]};
      const u32x4 f1 = {pk[4], pk[5], pk[6], pk[7]};
      const u32x4 f2 = {pk[8], pk[9], pk[10], pk[11]};
      const u32x4 f3 = {pk[12], pk[13], pk[14], pk[15]};
      const bf16x8 pa0 = __builtin_bit_cast(bf16x8, f0);
      const bf16x8 pa1 = __builtin_bit_cast(bf16x8, f1);
      const bf16x8 pa2 = __builtin_bit_cast(bf16x8, f2);
      const bf16x8 pa3 = __builtin_bit_cast(bf16x8, f3);

      // ---- PV cluster: boost priority while feeding the matrix pipe ----
      __builtin_amdgcn_s_setprio(1);
#pragma unroll
      for (int ks = 0; ks < 4; ++ks) {
        if (!(skipHi && ks >= 2)) {
          const bf16x8 pa = (ks == 0) ? pa0 : (ks == 1) ? pa1 : (ks == 2) ? pa2 : pa3;
          const bf16x8 va0 = *reinterpret_cast<const bf16x8*>(&Vt[l31][ks * 16 + hi2 * 8]);
          const bf16x8 va1 = *reinterpret_cast<const bf16x8*>(&Vt[32 + l31][ks * 16 + hi2 * 8]);
          y0 = __builtin_amdgcn_mfma_f32_32x32x16_bf16(va0, pa, y0, 0, 0, 0);
          y1 = __builtin_amdgcn_mfma_f32_32x32x16_bf16(va1, pa, y1, 0, 0, 0);
        }
      }
      __builtin_amdgcn_s_setprio(0);
    };

    for (int tt = w; tt < NT; tt += 4) {
      stageV(tt);
      bf16x8 kr[8];
      {
        const bf16* kp = K + (rb + tt * 64 + l31) * 1024 + hcol + hi2 * 8;
        const bf16* kp2 = kp + (size_t)32 * 1024;
#pragma unroll
        for (int i = 0; i < 4; ++i) {
          kr[i] = *reinterpret_cast<const bf16x8*>(kp + i * 16);
          kr[4 + i] = *reinterpret_cast<const bf16x8*>(kp2 + i * 16);
        }
      }
      const bool diag = (tt == qg);

      // ---- QK^T cluster: boost priority while feeding the matrix pipe ----
      __builtin_amdgcn_s_setprio(1);
      f32x16 sA0 = {}, sA1, sB0 = {}, sB1 = {};
      sA0 = __builtin_amdgcn_mfma_f32_32x32x16_bf16(kr[0], qfA[0], sA0, 0, 0, 0);
      sA0 = __builtin_amdgcn_mfma_f32_32x32x16_bf16(kr[1], qfA[1], sA0, 0, 0, 0);
      sA0 = __builtin_amdgcn_mfma_f32_32x32x16_bf16(kr[2], qfA[2], sA0, 0, 0, 0);
      sA0 = __builtin_amdgcn_mfma_f32_32x32x16_bf16(kr[3], qfA[3], sA0, 0, 0, 0);
      if (!diag) {
        f32x16 t0 = {};
        t0 = __builtin_amdgcn_mfma_f32_32x32x16_bf16(kr[4], qfA[0], t0, 0, 0, 0);
        t0 = __builtin_amdgcn_mfma_f32_32x32x16_bf16(kr[5], qfA[1], t0, 0, 0, 0);
        t0 = __builtin_amdgcn_mfma_f32_32x32x16_bf16(kr[6], qfA[2], t0, 0, 0, 0);
        t0 = __builtin_amdgcn_mfma_f32_32x32x16_bf16(kr[7], qfA[3], t0, 0, 0, 0);
        sA1 = t0;
      } else {
#pragma unroll
        for (int r = 0; r < 16; ++r) sA1[r] = -INFINITY;  // kv-high > all A rows
      }
      sB0 = __builtin_amdgcn_mfma_f32_32x32x16_bf16(kr[0], qfB[0], sB0, 0, 0, 0);
      sB0 = __builtin_amdgcn_mfma_f32_32x32x16_bf16(kr[1], qfB[1], sB0, 0, 0, 0);
      sB0 = __builtin_amdgcn_mfma_f32_32x32x16_bf16(kr[2], qfB[2], sB0, 0, 0, 0);
      sB0 = __builtin_amdgcn_mfma_f32_32x32x16_bf16(kr[3], qfB[3], sB0, 0, 0, 0);
      sB1 = __builtin_amdgcn_mfma_f32_32x32x16_bf16(kr[4], qfB[0], sB1, 0, 0, 0);
      sB1 = __builtin_amdgcn_mfma_f32_32x32x16_bf16(kr[5], qfB[1], sB1, 0, 0, 0);
      sB1 = __builtin_amdgcn_mfma_f32_32x32x16_bf16(kr[6], qfB[2], sB1, 0, 0, 0);
      sB1 = __builtin_amdgcn_mfma_f32_32x32x16_bf16(kr[7], qfB[3], sB1, 0, 0, 0);
      __builtin_amdgcn_s_setprio(0);

      if (diag) {
#pragma unroll
        for (int r = 0; r < 16; ++r) {
          const int kvl = (r & 3) + 8 * (r >> 2) + 4 * hi2;
          if (kvl > l31) sA0[r] = -INFINITY;  // A diag in kv-low
          if (kvl > l31) sB1[r] = -INFINITY;  // B diag in kv-high
        }
      }

      smax_pv64(sA0, sA1, mA, lA, yA0, yA1, diag);
      smax_pv64(sB0, sB1, mB, lB, yB0, yB1, false);
    }

    // ---- combine 4 wave-partials: 4 quarter-phases (A/B x d-half) ----
    __syncthreads();  // Vt dead; comb may alias it
    if (lane < 32) {
      mlS[w][0][l31] = mA;
      mlS[w][1][l31] = lA;
      mlS[w][0][32 + l31] = mB;
      mlS[w][1][32 + l31] = lB;
    }

    auto comb_phase = [&](const f32x16& y, int qoff, int dcol) {
#pragma unroll
      for (int r = 0; r < 16; r += 2) {
        const int d0 = (r & 3) + 8 * (r >> 2) + 4 * hi2;
        float2 v2;
        v2.x = y[r];
        v2.y = y[r + 1];
        *reinterpret_cast<float2*>(&combf[((size_t)w * 32 + l31) * 34 + d0]) = v2;
      }
      __syncthreads();

      const int tq = tid >> 3;       // 0..31 (q row within set)
      const int dg = (tid & 7) * 4;  // 0..28 (d offset within half)
      float mw[4], lw[4];
#pragma unroll
      for (int ww = 0; ww < 4; ++ww) {
        mw[ww] = mlS[ww][0][qoff + tq];
        lw[ww] = mlS[ww][1][qoff + tq];
      }
      const float M = fmaxf(fmaxf(mw[0], mw[1]), fmaxf(mw[2], mw[3]));
      float wg[4];
      float Lsum = 0.f;
#pragma unroll
      for (int ww = 0; ww < 4; ++ww) {
        wg[ww] = fexp2((mw[ww] - M) * cl2);
        Lsum += lw[ww] * wg[ww];
      }
      const float inv = 1.f / Lsum;
      float a4[4] = {};
#pragma unroll
      for (int ww = 0; ww < 4; ++ww)
#pragma unroll
        for (int jj = 0; jj < 4; ++jj)
          a4[jj] += wg[ww] * combf[((size_t)ww * 32 + tq) * 34 + dg + jj];
      bf16x4 o;
#pragma unroll
      for (int jj = 0; jj < 4; ++jj) o[jj] = (bf16)(a4[jj] * inv);
      *reinterpret_cast<bf16x4*>(Y + (rb + qbase + qoff + tq) * 1024 + hcol + dcol + dg) = o;
      __syncthreads();
    };

    comb_phase(yA0, 0, 0);
    comb_phase(yA1, 0, 32);
    comb_phase(yB0, 32, 0);
    comb_phase(yB1, 32, 32);
  };

  run(31 - jp);
  run(jp);
}

// ---------------- host launch ----------------------------------------------
extern "C" void kernel_launch(void* const* d_in, const int* in_sizes, int n_in,
                              void* d_out, int out_size, void* d_ws,
                              size_t ws_size, hipStream_t stream) {
  const float* x = (const float*)d_in[0];
  const float* Wq = (const float*)d_in[1];
  const float* bq = (const float*)d_in[2];
  const float* Wk = (const float*)d_in[3];
  const float* bk = (const float*)d_in[4];
  const float* Wv = (const float*)d_in[5];
  const float* bv = (const float*)d_in[6];
  const float* Wp = (const float*)d_in[7];
  const float* bp = (const float*)d_in[8];

  const int BS = 4096;
  const int Dm = 1024;

  char* ws = (char*)d_ws;
  bf16* xb = (bf16*)(ws);
  bf16* wqb = (bf16*)(ws + (size_t)(8 << 20));
  bf16* wkb = (bf16*)(ws + (size_t)(10 << 20));
  bf16* wvb = (bf16*)(ws + (size_t)(12 << 20));
  bf16* wpb = (bf16*)(ws + (size_t)(14 << 20));
  bf16* Qb = (bf16*)(ws + (size_t)(16 << 20));
  bf16* Kb = (bf16*)(ws + (size_t)(24 << 20));
  bf16* Vb = (bf16*)(ws + (size_t)(32 << 20));
  bf16* Yb = (bf16*)(ws + (size_t)(40 << 20));

  CvtArgs ca;
  ca.src[0] = x;  ca.dst[0] = xb;  ca.n[0] = BS * Dm;
  ca.src[1] = Wq; ca.dst[1] = wqb; ca.n[1] = Dm * Dm;
  ca.src[2] = Wk; ca.dst[2] = wkb; ca.n[2] = Dm * Dm;
  ca.src[3] = Wv; ca.dst[3] = wvb; ca.n[3] = Dm * Dm;
  ca.src[4] = Wp; ca.dst[4] = wpb; ca.n[4] = Dm * Dm;
  cvt_multi<<<dim3(1024, 5), 256, 0, stream>>>(ca);

  GemmBatch gq;
  gq.Bw[0] = wqb; gq.bias[0] = bq; gq.C[0] = Qb;
  gq.Bw[1] = wkb; gq.bias[1] = bk; gq.C[1] = Kb;
  gq.Bw[2] = wvb; gq.bias[2] = bv; gq.C[2] = Vb;
  gemm128<true><<<dim3(32, 8, 3), 256, 0, stream>>>(xb, gq, BS, Dm, Dm);

  attn_ws<<<dim3(512), 256, 0, stream>>>(Qb, Kb, Vb, Yb);

  GemmBatch gp;
  gp.Bw[0] = wpb; gp.bias[0] = bp; gp.C[0] = d_out;
  gp.Bw[1] = wpb; gp.bias[1] = bp; gp.C[1] = d_out;
  gp.Bw[2] = wpb; gp.bias[2] = bp; gp.C[2] = d_out;
  gemm128<false><<<dim3(32, 8, 1), 256, 0, stream>>>(Yb, gp, BS, Dm, Dm);
}

// Round 24
// 122.036 us; speedup vs baseline: 1.1042x; 1.0009x over previous
//
#include <hip/hip_runtime.h>
#include <hip/hip_bf16.h>

typedef __bf16 bf16;
typedef bf16 bf16x4 __attribute__((ext_vector_type(4)));
typedef bf16 bf16x8 __attribute__((ext_vector_type(8)));
typedef float f32x4 __attribute__((ext_vector_type(4)));
typedef float f32x16 __attribute__((ext_vector_type(16)));
typedef unsigned int u32x4 __attribute__((ext_vector_type(4)));

#define LOG2E 1.44269504088896340736f

__device__ __forceinline__ void gload_lds16(const bf16* g, bf16* l) {
  __builtin_amdgcn_global_load_lds(
      (const __attribute__((address_space(1))) void*)g,
      (__attribute__((address_space(3))) void*)l, 16, 0, 0);
}

// raw v_exp_f32 (2^x): args here are always <= ~8, -inf ok (-> 0)
__device__ __forceinline__ float fexp2(float x) {
  float r;
  asm("v_exp_f32 %0, %1" : "=v"(r) : "v"(x));
  return r;
}

// ---------------- fp32 -> bf16 conversion (5 segments in one launch) -------
struct CvtArgs {
  const float* src[5];
  bf16* dst[5];
  int n[5];
};

__global__ __launch_bounds__(256) void cvt_multi(CvtArgs a) {
  const int seg = blockIdx.y;
  const float* __restrict__ s = a.src[seg];
  bf16* __restrict__ d = a.dst[seg];
  const int n = a.n[seg];
  int i = (blockIdx.x * 256 + threadIdx.x) * 4;
  const int stride = gridDim.x * 256 * 4;
  for (; i < n; i += stride) {
    float4 f = *reinterpret_cast<const float4*>(s + i);
    bf16x4 o = {(bf16)f.x, (bf16)f.y, (bf16)f.z, (bf16)f.w};
    *reinterpret_cast<bf16x4*>(d + i) = o;
  }
}

// ---------------- 128x128 bf16 GEMM (BK=64), C = A * B^T + bias ------------
// BK=64 (r18: -4us vs BK=32 -- halves per-iteration vmcnt(0)+barrier drains).
struct GemmBatch {
  const bf16* Bw[3];
  const float* bias[3];
  void* C[3];
};

template <bool OUT_BF16>
__global__ __launch_bounds__(256, 2) void gemm128(const bf16* __restrict__ A,
                                                  GemmBatch gb, int M, int N,
                                                  int K) {
  const int tid = threadIdx.x;
  const int wid = tid >> 6;
  const int lane = tid & 63;
  const int l16 = lane & 15;
  const int hi = lane >> 4;
  const int m0 = blockIdx.x * 128;
  const int n0 = blockIdx.y * 128;
  const int z = blockIdx.z;
  const bf16* __restrict__ Bw = gb.Bw[z];
  const float* __restrict__ bias = gb.bias[z];

  __shared__ bf16 As[128 * 64];
  __shared__ bf16 Bs[128 * 64];

  f32x4 acc[4][4] = {};

  const int wm = (wid >> 1) * 64;
  const int wn = (wid & 1) * 64;

  for (int k0 = 0; k0 < K; k0 += 64) {
#pragma unroll
    for (int i = 0; i < 4; ++i) {
      const int chunk = wid + 4 * i;               // 0..15, wave-uniform
      const int p = chunk * 1024 + lane * 16;      // physical LDS byte
      const int row = p >> 7;                      // 128B per row (64 bf16)
      const int cb = (p & 112) ^ ((row & 3) << 4); // logical col byte
      gload_lds16(A + (size_t)(m0 + row) * K + k0 + (cb >> 1), As + chunk * 512);
      gload_lds16(Bw + (size_t)(n0 + row) * K + k0 + (cb >> 1), Bs + chunk * 512);
    }
    __syncthreads();

#pragma unroll
    for (int ks = 0; ks < 2; ++ks) {
      bf16x8 af[4], bfr[4];
#pragma unroll
      for (int m = 0; m < 4; ++m) {
        const int r = wm + m * 16 + l16;
        const int pb = r * 128 + ((ks * 64 + hi * 16) ^ ((r & 3) << 4));
        af[m] = *reinterpret_cast<const bf16x8*>((const char*)As + pb);
      }
#pragma unroll
      for (int n = 0; n < 4; ++n) {
        const int r = wn + n * 16 + l16;
        const int pb = r * 128 + ((ks * 64 + hi * 16) ^ ((r & 3) << 4));
        bfr[n] = *reinterpret_cast<const bf16x8*>((const char*)Bs + pb);
      }
#pragma unroll
      for (int m = 0; m < 4; ++m)
#pragma unroll
        for (int n = 0; n < 4; ++n)
          acc[m][n] =
              __builtin_amdgcn_mfma_f32_16x16x32_bf16(af[m], bfr[n], acc[m][n], 0, 0, 0);
    }
    __syncthreads();
  }

  const int rbase = m0 + wm + hi * 4;
  const int cbase = n0 + wn + l16;
#pragma unroll
  for (int n = 0; n < 4; ++n) {
    const int col = cbase + n * 16;
    const float bv = bias[col];
#pragma unroll
    for (int m = 0; m < 4; ++m) {
#pragma unroll
      for (int j = 0; j < 4; ++j) {
        const int row = rbase + m * 16 + j;
        const float v = acc[m][n][j] + bv;
        if (OUT_BF16)
          ((bf16*)gb.C[z])[(size_t)row * N + col] = (bf16)v;
        else
          ((float*)gb.C[z])[(size_t)row * N + col] = v;
      }
    }
  }
}

// ---------------- causal flash attention, wave-split KV, 64q x 64kv --------
// r24 = r23 (64.7us attn: r20 + T5 setprio, confirmed) + merged combine:
// pairs (yA0,yA1) and (yB0,yB1) written 66-float-wide in ONE phase each
// (r4/r6-proven layout; comb 33.8KB aliases Vt 36.9KB) -> 4 phases/run
// becomes 2, saving 8 barriers+round-trips per block. Expected ~5e5 LDS
// conflict count reappears (r6: cost-neutral).
__global__ __launch_bounds__(256, 2) void attn_ws(const bf16* __restrict__ Q,
                                                  const bf16* __restrict__ K,
                                                  const bf16* __restrict__ V,
                                                  bf16* __restrict__ Y) {
  const int p = blockIdx.x;    // 0..511
  const int bh = p & 31;       // XCD p%8 sees streams {bh : bh%8 == p%8}
  const int jp = p >> 5;       // 0..15
  const int h = bh & 15;
  const int b = bh >> 4;

  const int tid = threadIdx.x;
  const int w = tid >> 6;
  const int lane = tid & 63;
  const int l31 = lane & 31;
  const int hi2 = lane >> 5;
  const size_t rb = (size_t)b * 2048;
  const int hcol = h * 64;
  const float cl2 = 0.125f * LOG2E;

  __shared__ char smem[36864];
  __shared__ float mlS[4][2][64];
  bf16(*Vt)[72] = (bf16(*)[72])(smem + (size_t)w * 9216);
  float* combf = (float*)smem;

  const int kvg = lane & 7;   // staging: kv quad group
  const int dgr = lane >> 3;  // staging: d quad group (0..7)

  auto stageV = [&](int tt) {
    const bf16* vp0 = V + (rb + tt * 64 + kvg * 4) * 1024 + hcol + dgr * 4;
#pragma unroll
    for (int hh = 0; hh < 2; ++hh) {
      const bf16* vp = vp0 + (size_t)hh * 32 * 1024;
      bf16x4 vr[2][4];
#pragma unroll
      for (int r = 0; r < 2; ++r)
#pragma unroll
        for (int jj = 0; jj < 4; ++jj)
          vr[r][jj] = *reinterpret_cast<const bf16x4*>(vp + (size_t)jj * 1024 + r * 32);
#pragma unroll
      for (int r = 0; r < 2; ++r)
#pragma unroll
        for (int kc = 0; kc < 4; ++kc) {
          bf16x4 wv = {vr[r][0][kc], vr[r][1][kc], vr[r][2][kc], vr[r][3][kc]};
          *reinterpret_cast<bf16x4*>(&Vt[r * 32 + dgr * 4 + kc][hh * 32 + kvg * 4]) = wv;
        }
    }
  };

  auto run = [&](int qg) {
    const int qbase = qg * 64;
    const int NT = qg + 1;  // kv tiles of 64

    bf16x8 qfA[4], qfB[4];
    {
      const bf16* qpA = Q + (rb + qbase + l31) * 1024 + hcol + hi2 * 8;
      const bf16* qpB = qpA + (size_t)32 * 1024;
#pragma unroll
      for (int kt = 0; kt < 4; ++kt) {
        qfA[kt] = *reinterpret_cast<const bf16x8*>(qpA + kt * 16);
        qfB[kt] = *reinterpret_cast<const bf16x8*>(qpB + kt * 16);
      }
    }

    f32x16 yA0 = {}, yA1 = {}, yB0 = {}, yB1 = {};
    float mA = -INFINITY, lA = 0.f, mB = -INFINITY, lB = 0.f;

    auto smax_pv64 = [&](f32x16& s0, f32x16& s1, float& m, float& l,
                         f32x16& y0, f32x16& y1, bool skipHi) {
      float red[8];
#pragma unroll
      for (int i = 0; i < 8; ++i)
        red[i] = fmaxf(fmaxf(s0[i], s0[i + 8]), fmaxf(s1[i], s1[i + 8]));
#pragma unroll
      for (int i = 0; i < 4; ++i) red[i] = fmaxf(red[i], red[i + 4]);
      float pm = fmaxf(fmaxf(red[0], red[1]), fmaxf(red[2], red[3]));
      pm = fmaxf(pm, __shfl_xor(pm, 32));

      if (!__all(pm <= m + 40.f)) {  // defer-max (T13)
        const float mn = fmaxf(m, pm);
        const float al = fexp2((m - mn) * cl2);
#pragma unroll
        for (int r = 0; r < 16; ++r) {
          y0[r] *= al;
          y1[r] *= al;
        }
        l *= al;
        m = mn;
      }
      const float mc = m * cl2;
      float ps[32];
#pragma unroll
      for (int r = 0; r < 16; ++r) ps[r] = fexp2(s0[r] * cl2 - mc);
#pragma unroll
      for (int r = 0; r < 16; ++r) ps[16 + r] = fexp2(s1[r] * cl2 - mc);
      float sum[16];
#pragma unroll
      for (int i = 0; i < 16; ++i) sum[i] = ps[i] + ps[i + 16];
#pragma unroll
      for (int i = 0; i < 8; ++i) sum[i] += sum[i + 8];
#pragma unroll
      for (int i = 0; i < 4; ++i) sum[i] += sum[i + 4];
      float rs = (sum[0] + sum[1]) + (sum[2] + sum[3]);
      rs += __shfl_xor(rs, 32);
      l += rs;

      unsigned int pk[16];
#pragma unroll
      for (int i = 0; i < 16; ++i) {
        const unsigned short a = __builtin_bit_cast(unsigned short, (bf16)ps[2 * i]);
        const unsigned short c = __builtin_bit_cast(unsigned short, (bf16)ps[2 * i + 1]);
        pk[i] = (unsigned int)a | ((unsigned int)c << 16);
      }
      asm("v_permlane32_swap_b32 %0, %1" : "+v"(pk[0]), "+v"(pk[2]));
      asm("v_permlane32_swap_b32 %0, %1" : "+v"(pk[1]), "+v"(pk[3]));
      asm("v_permlane32_swap_b32 %0, %1" : "+v"(pk[4]), "+v"(pk[6]));
      asm("v_permlane32_swap_b32 %0, %1" : "+v"(pk[5]), "+v"(pk[7]));
      asm("v_permlane32_swap_b32 %0, %1" : "+v"(pk[8]), "+v"(pk[10]));
      asm("v_permlane32_swap_b32 %0, %1" : "+v"(pk[9]), "+v"(pk[11]));
      asm("v_permlane32_swap_b32 %0, %1" : "+v"(pk[12]), "+v"(pk[14]));
      asm("v_permlane32_swap_b32 %0, %1" : "+v"(pk[13]), "+v"(pk[15]));
      const u32x4 f0 = {pk[0], pk[1], pk[2], pk[3]};
      const u32x4 f1 = {pk[4], pk[5], pk[6], pk[7]};
      const u32x4 f2 = {pk[8], pk[9], pk[10], pk[11]};
      const u32x4 f3 = {pk[12], pk[13], pk[14], pk[15]};
      const bf16x8 pa0 = __builtin_bit_cast(bf16x8, f0);
      const bf16x8 pa1 = __builtin_bit_cast(bf16x8, f1);
      const bf16x8 pa2 = __builtin_bit_cast(bf16x8, f2);
      const bf16x8 pa3 = __builtin_bit_cast(bf16x8, f3);

      // ---- PV cluster: boost priority while feeding the matrix pipe ----
      __builtin_amdgcn_s_setprio(1);
#pragma unroll
      for (int ks = 0; ks < 4; ++ks) {
        if (!(skipHi && ks >= 2)) {
          const bf16x8 pa = (ks == 0) ? pa0 : (ks == 1) ? pa1 : (ks == 2) ? pa2 : pa3;
          const bf16x8 va0 = *reinterpret_cast<const bf16x8*>(&Vt[l31][ks * 16 + hi2 * 8]);
          const bf16x8 va1 = *reinterpret_cast<const bf16x8*>(&Vt[32 + l31][ks * 16 + hi2 * 8]);
          y0 = __builtin_amdgcn_mfma_f32_32x32x16_bf16(va0, pa, y0, 0, 0, 0);
          y1 = __builtin_amdgcn_mfma_f32_32x32x16_bf16(va1, pa, y1, 0, 0, 0);
        }
      }
      __builtin_amdgcn_s_setprio(0);
    };

    for (int tt = w; tt < NT; tt += 4) {
      stageV(tt);
      bf16x8 kr[8];
      {
        const bf16* kp = K + (rb + tt * 64 + l31) * 1024 + hcol + hi2 * 8;
        const bf16* kp2 = kp + (size_t)32 * 1024;
#pragma unroll
        for (int i = 0; i < 4; ++i) {
          kr[i] = *reinterpret_cast<const bf16x8*>(kp + i * 16);
          kr[4 + i] = *reinterpret_cast<const bf16x8*>(kp2 + i * 16);
        }
      }
      const bool diag = (tt == qg);

      // ---- QK^T cluster: boost priority while feeding the matrix pipe ----
      __builtin_amdgcn_s_setprio(1);
      f32x16 sA0 = {}, sA1, sB0 = {}, sB1 = {};
      sA0 = __builtin_amdgcn_mfma_f32_32x32x16_bf16(kr[0], qfA[0], sA0, 0, 0, 0);
      sA0 = __builtin_amdgcn_mfma_f32_32x32x16_bf16(kr[1], qfA[1], sA0, 0, 0, 0);
      sA0 = __builtin_amdgcn_mfma_f32_32x32x16_bf16(kr[2], qfA[2], sA0, 0, 0, 0);
      sA0 = __builtin_amdgcn_mfma_f32_32x32x16_bf16(kr[3], qfA[3], sA0, 0, 0, 0);
      if (!diag) {
        f32x16 t0 = {};
        t0 = __builtin_amdgcn_mfma_f32_32x32x16_bf16(kr[4], qfA[0], t0, 0, 0, 0);
        t0 = __builtin_amdgcn_mfma_f32_32x32x16_bf16(kr[5], qfA[1], t0, 0, 0, 0);
        t0 = __builtin_amdgcn_mfma_f32_32x32x16_bf16(kr[6], qfA[2], t0, 0, 0, 0);
        t0 = __builtin_amdgcn_mfma_f32_32x32x16_bf16(kr[7], qfA[3], t0, 0, 0, 0);
        sA1 = t0;
      } else {
#pragma unroll
        for (int r = 0; r < 16; ++r) sA1[r] = -INFINITY;  // kv-high > all A rows
      }
      sB0 = __builtin_amdgcn_mfma_f32_32x32x16_bf16(kr[0], qfB[0], sB0, 0, 0, 0);
      sB0 = __builtin_amdgcn_mfma_f32_32x32x16_bf16(kr[1], qfB[1], sB0, 0, 0, 0);
      sB0 = __builtin_amdgcn_mfma_f32_32x32x16_bf16(kr[2], qfB[2], sB0, 0, 0, 0);
      sB0 = __builtin_amdgcn_mfma_f32_32x32x16_bf16(kr[3], qfB[3], sB0, 0, 0, 0);
      sB1 = __builtin_amdgcn_mfma_f32_32x32x16_bf16(kr[4], qfB[0], sB1, 0, 0, 0);
      sB1 = __builtin_amdgcn_mfma_f32_32x32x16_bf16(kr[5], qfB[1], sB1, 0, 0, 0);
      sB1 = __builtin_amdgcn_mfma_f32_32x32x16_bf16(kr[6], qfB[2], sB1, 0, 0, 0);
      sB1 = __builtin_amdgcn_mfma_f32_32x32x16_bf16(kr[7], qfB[3], sB1, 0, 0, 0);
      __builtin_amdgcn_s_setprio(0);

      if (diag) {
#pragma unroll
        for (int r = 0; r < 16; ++r) {
          const int kvl = (r & 3) + 8 * (r >> 2) + 4 * hi2;
          if (kvl > l31) sA0[r] = -INFINITY;  // A diag in kv-low
          if (kvl > l31) sB1[r] = -INFINITY;  // B diag in kv-high
        }
      }

      smax_pv64(sA0, sA1, mA, lA, yA0, yA1, diag);
      smax_pv64(sB0, sB1, mB, lB, yB0, yB1, false);
    }

    // ---- combine 4 wave-partials: 2 merged phases (A pair, B pair) ----
    __syncthreads();  // Vt dead; comb may alias it
    if (lane < 32) {
      mlS[w][0][l31] = mA;
      mlS[w][1][l31] = lA;
      mlS[w][0][32 + l31] = mB;
      mlS[w][1][32 + l31] = lB;
    }

    auto comb_pair = [&](const f32x16& y0, const f32x16& y1, int qoff) {
#pragma unroll
      for (int r = 0; r < 16; r += 2) {
        const int d0 = (r & 3) + 8 * (r >> 2) + 4 * hi2;
        float2 v2a;
        v2a.x = y0[r];
        v2a.y = y0[r + 1];
        *reinterpret_cast<float2*>(&combf[((size_t)w * 32 + l31) * 66 + d0]) = v2a;
        float2 v2b;
        v2b.x = y1[r];
        v2b.y = y1[r + 1];
        *reinterpret_cast<float2*>(&combf[((size_t)w * 32 + l31) * 66 + d0 + 32]) = v2b;
      }
      __syncthreads();

      const int tq = tid >> 3;       // 0..31 (q row within set)
      const int dg = (tid & 7) * 8;  // 0..56 (d offset, 8 floats/thread)
      float mw[4], lw[4];
#pragma unroll
      for (int ww = 0; ww < 4; ++ww) {
        mw[ww] = mlS[ww][0][qoff + tq];
        lw[ww] = mlS[ww][1][qoff + tq];
      }
      const float M = fmaxf(fmaxf(mw[0], mw[1]), fmaxf(mw[2], mw[3]));
      float wg[4];
      float Lsum = 0.f;
#pragma unroll
      for (int ww = 0; ww < 4; ++ww) {
        wg[ww] = fexp2((mw[ww] - M) * cl2);
        Lsum += lw[ww] * wg[ww];
      }
      const float inv = 1.f / Lsum;
      float a8[8] = {};
#pragma unroll
      for (int ww = 0; ww < 4; ++ww)
#pragma unroll
        for (int jj = 0; jj < 8; ++jj)
          a8[jj] += wg[ww] * combf[((size_t)ww * 32 + tq) * 66 + dg + jj];
      bf16x8 o;
#pragma unroll
      for (int jj = 0; jj < 8; ++jj) o[jj] = (bf16)(a8[jj] * inv);
      *reinterpret_cast<bf16x8*>(Y + (rb + qbase + qoff + tq) * 1024 + hcol + dg) = o;
      __syncthreads();
    };

    comb_pair(yA0, yA1, 0);
    comb_pair(yB0, yB1, 32);
  };

  run(31 - jp);
  run(jp);
}

// ---------------- host launch ----------------------------------------------
extern "C" void kernel_launch(void* const* d_in, const int* in_sizes, int n_in,
                              void* d_out, int out_size, void* d_ws,
                              size_t ws_size, hipStream_t stream) {
  const float* x = (const float*)d_in[0];
  const float* Wq = (const float*)d_in[1];
  const float* bq = (const float*)d_in[2];
  const float* Wk = (const float*)d_in[3];
  const float* bk = (const float*)d_in[4];
  const float* Wv = (const float*)d_in[5];
  const float* bv = (const float*)d_in[6];
  const float* Wp = (const float*)d_in[7];
  const float* bp = (const float*)d_in[8];

  const int BS = 4096;
  const int Dm = 1024;

  char* ws = (char*)d_ws;
  bf16* xb = (bf16*)(ws);
  bf16* wqb = (bf16*)(ws + (size_t)(8 << 20));
  bf16* wkb = (bf16*)(ws + (size_t)(10 << 20));
  bf16* wvb = (bf16*)(ws + (size_t)(12 << 20));
  bf16* wpb = (bf16*)(ws + (size_t)(14 << 20));
  bf16* Qb = (bf16*)(ws + (size_t)(16 << 20));
  bf16* Kb = (bf16*)(ws + (size_t)(24 << 20));
  bf16* Vb = (bf16*)(ws + (size_t)(32 << 20));
  bf16* Yb = (bf16*)(ws + (size_t)(40 << 20));

  CvtArgs ca;
  ca.src[0] = x;  ca.dst[0] = xb;  ca.n[0] = BS * Dm;
  ca.src[1] = Wq; ca.dst[1] = wqb; ca.n[1] = Dm * Dm;
  ca.src[2] = Wk; ca.dst[2] = wkb; ca.n[2] = Dm * Dm;
  ca.src[3] = Wv; ca.dst[3] = wvb; ca.n[3] = Dm * Dm;
  ca.src[4] = Wp; ca.dst[4] = wpb; ca.n[4] = Dm * Dm;
  cvt_multi<<<dim3(1024, 5), 256, 0, stream>>>(ca);

  GemmBatch gq;
  gq.Bw[0] = wqb; gq.bias[0] = bq; gq.C[0] = Qb;
  gq.Bw[1] = wkb; gq.bias[1] = bk; gq.C[1] = Kb;
  gq.Bw[2] = wvb; gq.bias[2] = bv; gq.C[2] = Vb;
  gemm128<true><<<dim3(32, 8, 3), 256, 0, stream>>>(xb, gq, BS, Dm, Dm);

  attn_ws<<<dim3(512), 256, 0, stream>>>(Qb, Kb, Vb, Yb);

  GemmBatch gp;
  gp.Bw[0] = wpb; gp.bias[0] = bp; gp.C[0] = d_out;
  gp.Bw[1] = wpb; gp.bias[1] = bp; gp.C[1] = d_out;
  gp.Bw[2] = wpb; gp.bias[2] = bp; gp.C[2] = d_out;
  gemm128<false><<<dim3(32, 8, 1), 256, 0, stream>>>(Yb, gp, BS, Dm, Dm);
}

// Round 25
// 121.887 us; speedup vs baseline: 1.1056x; 1.0012x over previous
//
#include <hip/hip_runtime.h>
#include <hip/hip_bf16.h>

typedef __bf16 bf16;
typedef bf16 bf16x4 __attribute__((ext_vector_type(4)));
typedef bf16 bf16x8 __attribute__((ext_vector_type(8)));
typedef float f32x4 __attribute__((ext_vector_type(4)));
typedef float f32x16 __attribute__((ext_vector_type(16)));
typedef unsigned int u32x4 __attribute__((ext_vector_type(4)));

#define LOG2E 1.44269504088896340736f

__device__ __forceinline__ void gload_lds16(const bf16* g, bf16* l) {
  __builtin_amdgcn_global_load_lds(
      (const __attribute__((address_space(1))) void*)g,
      (__attribute__((address_space(3))) void*)l, 16, 0, 0);
}

// raw v_exp_f32 (2^x): args here are always <= ~8, -inf ok (-> 0)
__device__ __forceinline__ float fexp2(float x) {
  float r;
  asm("v_exp_f32 %0, %1" : "=v"(r) : "v"(x));
  return r;
}

// ---------------- fp32 -> bf16 conversion (5 segments in one launch) -------
struct CvtArgs {
  const float* src[5];
  bf16* dst[5];
  int n[5];
};

__global__ __launch_bounds__(256) void cvt_multi(CvtArgs a) {
  const int seg = blockIdx.y;
  const float* __restrict__ s = a.src[seg];
  bf16* __restrict__ d = a.dst[seg];
  const int n = a.n[seg];
  int i = (blockIdx.x * 256 + threadIdx.x) * 4;
  const int stride = gridDim.x * 256 * 4;
  for (; i < n; i += stride) {
    float4 f = *reinterpret_cast<const float4*>(s + i);
    bf16x4 o = {(bf16)f.x, (bf16)f.y, (bf16)f.z, (bf16)f.w};
    *reinterpret_cast<bf16x4*>(d + i) = o;
  }
}

// ---------------- 128x128 bf16 GEMM (BK=64), C = A * B^T + bias ------------
// BK=64 (r18: -4us vs BK=32 -- halves per-iteration vmcnt(0)+barrier drains).
struct GemmBatch {
  const bf16* Bw[3];
  const float* bias[3];
  void* C[3];
};

template <bool OUT_BF16>
__global__ __launch_bounds__(256, 2) void gemm128(const bf16* __restrict__ A,
                                                  GemmBatch gb, int M, int N,
                                                  int K) {
  const int tid = threadIdx.x;
  const int wid = tid >> 6;
  const int lane = tid & 63;
  const int l16 = lane & 15;
  const int hi = lane >> 4;
  const int m0 = blockIdx.x * 128;
  const int n0 = blockIdx.y * 128;
  const int z = blockIdx.z;
  const bf16* __restrict__ Bw = gb.Bw[z];
  const float* __restrict__ bias = gb.bias[z];

  __shared__ bf16 As[128 * 64];
  __shared__ bf16 Bs[128 * 64];

  f32x4 acc[4][4] = {};

  const int wm = (wid >> 1) * 64;
  const int wn = (wid & 1) * 64;

  for (int k0 = 0; k0 < K; k0 += 64) {
#pragma unroll
    for (int i = 0; i < 4; ++i) {
      const int chunk = wid + 4 * i;               // 0..15, wave-uniform
      const int p = chunk * 1024 + lane * 16;      // physical LDS byte
      const int row = p >> 7;                      // 128B per row (64 bf16)
      const int cb = (p & 112) ^ ((row & 3) << 4); // logical col byte
      gload_lds16(A + (size_t)(m0 + row) * K + k0 + (cb >> 1), As + chunk * 512);
      gload_lds16(Bw + (size_t)(n0 + row) * K + k0 + (cb >> 1), Bs + chunk * 512);
    }
    __syncthreads();

#pragma unroll
    for (int ks = 0; ks < 2; ++ks) {
      bf16x8 af[4], bfr[4];
#pragma unroll
      for (int m = 0; m < 4; ++m) {
        const int r = wm + m * 16 + l16;
        const int pb = r * 128 + ((ks * 64 + hi * 16) ^ ((r & 3) << 4));
        af[m] = *reinterpret_cast<const bf16x8*>((const char*)As + pb);
      }
#pragma unroll
      for (int n = 0; n < 4; ++n) {
        const int r = wn + n * 16 + l16;
        const int pb = r * 128 + ((ks * 64 + hi * 16) ^ ((r & 3) << 4));
        bfr[n] = *reinterpret_cast<const bf16x8*>((const char*)Bs + pb);
      }
#pragma unroll
      for (int m = 0; m < 4; ++m)
#pragma unroll
        for (int n = 0; n < 4; ++n)
          acc[m][n] =
              __builtin_amdgcn_mfma_f32_16x16x32_bf16(af[m], bfr[n], acc[m][n], 0, 0, 0);
    }
    __syncthreads();
  }

  const int rbase = m0 + wm + hi * 4;
  const int cbase = n0 + wn + l16;
#pragma unroll
  for (int n = 0; n < 4; ++n) {
    const int col = cbase + n * 16;
    const float bv = bias[col];
#pragma unroll
    for (int m = 0; m < 4; ++m) {
#pragma unroll
      for (int j = 0; j < 4; ++j) {
        const int row = rbase + m * 16 + j;
        const float v = acc[m][n][j] + bv;
        if (OUT_BF16)
          ((bf16*)gb.C[z])[(size_t)row * N + col] = (bf16)v;
        else
          ((float*)gb.C[z])[(size_t)row * N + col] = v;
      }
    }
  }
}

// ---------------- causal flash attention, wave-split KV, 64q x 64kv --------
// FINAL (r24, validated 2x: attn 63.8us, total 122.0us; session 231.6->122.0).
// 512 paired blocks x 256 threads; uniform 33 KV64-tiles/block; TWO 32x32x64
// score sets per tile sharing K frags and one Vt[64][72] staging; batched
// softmax per 64 kv; T5 setprio around MFMA clusters (r23: -1.8us); merged
// 2-phase combine (r24: -0.9us).
// Banked wins: wave-split KV + swapped QK^T (r4), LDS/grid shaping (r9),
// 2 q-sets/wave ILP (r13, +50%), GEMM BK=64 (r18), T5 (r23), merge (r24).
// Falsified (do not retry without disasm): VGPR caps below live set (r7),
// prefetch pinning via sched_barrier/asm (r11/r12), permlane copy-swap
// helper (r10/r14), KVBLK amortization (r17), 8-wave blocks (r19),
// 4 q-sets (r21 spills).
__global__ __launch_bounds__(256, 2) void attn_ws(const bf16* __restrict__ Q,
                                                  const bf16* __restrict__ K,
                                                  const bf16* __restrict__ V,
                                                  bf16* __restrict__ Y) {
  const int p = blockIdx.x;    // 0..511
  const int bh = p & 31;       // XCD p%8 sees streams {bh : bh%8 == p%8}
  const int jp = p >> 5;       // 0..15
  const int h = bh & 15;
  const int b = bh >> 4;

  const int tid = threadIdx.x;
  const int w = tid >> 6;
  const int lane = tid & 63;
  const int l31 = lane & 31;
  const int hi2 = lane >> 5;
  const size_t rb = (size_t)b * 2048;
  const int hcol = h * 64;
  const float cl2 = 0.125f * LOG2E;

  __shared__ char smem[36864];
  __shared__ float mlS[4][2][64];
  bf16(*Vt)[72] = (bf16(*)[72])(smem + (size_t)w * 9216);
  float* combf = (float*)smem;

  const int kvg = lane & 7;   // staging: kv quad group
  const int dgr = lane >> 3;  // staging: d quad group (0..7)

  auto stageV = [&](int tt) {
    const bf16* vp0 = V + (rb + tt * 64 + kvg * 4) * 1024 + hcol + dgr * 4;
#pragma unroll
    for (int hh = 0; hh < 2; ++hh) {
      const bf16* vp = vp0 + (size_t)hh * 32 * 1024;
      bf16x4 vr[2][4];
#pragma unroll
      for (int r = 0; r < 2; ++r)
#pragma unroll
        for (int jj = 0; jj < 4; ++jj)
          vr[r][jj] = *reinterpret_cast<const bf16x4*>(vp + (size_t)jj * 1024 + r * 32);
#pragma unroll
      for (int r = 0; r < 2; ++r)
#pragma unroll
        for (int kc = 0; kc < 4; ++kc) {
          bf16x4 wv = {vr[r][0][kc], vr[r][1][kc], vr[r][2][kc], vr[r][3][kc]};
          *reinterpret_cast<bf16x4*>(&Vt[r * 32 + dgr * 4 + kc][hh * 32 + kvg * 4]) = wv;
        }
    }
  };

  auto run = [&](int qg) {
    const int qbase = qg * 64;
    const int NT = qg + 1;  // kv tiles of 64

    bf16x8 qfA[4], qfB[4];
    {
      const bf16* qpA = Q + (rb + qbase + l31) * 1024 + hcol + hi2 * 8;
      const bf16* qpB = qpA + (size_t)32 * 1024;
#pragma unroll
      for (int kt = 0; kt < 4; ++kt) {
        qfA[kt] = *reinterpret_cast<const bf16x8*>(qpA + kt * 16);
        qfB[kt] = *reinterpret_cast<const bf16x8*>(qpB + kt * 16);
      }
    }

    f32x16 yA0 = {}, yA1 = {}, yB0 = {}, yB1 = {};
    float mA = -INFINITY, lA = 0.f, mB = -INFINITY, lB = 0.f;

    auto smax_pv64 = [&](f32x16& s0, f32x16& s1, float& m, float& l,
                         f32x16& y0, f32x16& y1, bool skipHi) {
      float red[8];
#pragma unroll
      for (int i = 0; i < 8; ++i)
        red[i] = fmaxf(fmaxf(s0[i], s0[i + 8]), fmaxf(s1[i], s1[i + 8]));
#pragma unroll
      for (int i = 0; i < 4; ++i) red[i] = fmaxf(red[i], red[i + 4]);
      float pm = fmaxf(fmaxf(red[0], red[1]), fmaxf(red[2], red[3]));
      pm = fmaxf(pm, __shfl_xor(pm, 32));

      if (!__all(pm <= m + 40.f)) {  // defer-max (T13)
        const float mn = fmaxf(m, pm);
        const float al = fexp2((m - mn) * cl2);
#pragma unroll
        for (int r = 0; r < 16; ++r) {
          y0[r] *= al;
          y1[r] *= al;
        }
        l *= al;
        m = mn;
      }
      const float mc = m * cl2;
      float ps[32];
#pragma unroll
      for (int r = 0; r < 16; ++r) ps[r] = fexp2(s0[r] * cl2 - mc);
#pragma unroll
      for (int r = 0; r < 16; ++r) ps[16 + r] = fexp2(s1[r] * cl2 - mc);
      float sum[16];
#pragma unroll
      for (int i = 0; i < 16; ++i) sum[i] = ps[i] + ps[i + 16];
#pragma unroll
      for (int i = 0; i < 8; ++i) sum[i] += sum[i + 8];
#pragma unroll
      for (int i = 0; i < 4; ++i) sum[i] += sum[i + 4];
      float rs = (sum[0] + sum[1]) + (sum[2] + sum[3]);
      rs += __shfl_xor(rs, 32);
      l += rs;

      unsigned int pk[16];
#pragma unroll
      for (int i = 0; i < 16; ++i) {
        const unsigned short a = __builtin_bit_cast(unsigned short, (bf16)ps[2 * i]);
        const unsigned short c = __builtin_bit_cast(unsigned short, (bf16)ps[2 * i + 1]);
        pk[i] = (unsigned int)a | ((unsigned int)c << 16);
      }
      asm("v_permlane32_swap_b32 %0, %1" : "+v"(pk[0]), "+v"(pk[2]));
      asm("v_permlane32_swap_b32 %0, %1" : "+v"(pk[1]), "+v"(pk[3]));
      asm("v_permlane32_swap_b32 %0, %1" : "+v"(pk[4]), "+v"(pk[6]));
      asm("v_permlane32_swap_b32 %0, %1" : "+v"(pk[5]), "+v"(pk[7]));
      asm("v_permlane32_swap_b32 %0, %1" : "+v"(pk[8]), "+v"(pk[10]));
      asm("v_permlane32_swap_b32 %0, %1" : "+v"(pk[9]), "+v"(pk[11]));
      asm("v_permlane32_swap_b32 %0, %1" : "+v"(pk[12]), "+v"(pk[14]));
      asm("v_permlane32_swap_b32 %0, %1" : "+v"(pk[13]), "+v"(pk[15]));
      const u32x4 f0 = {pk[0], pk[1], pk[2], pk[3]};
      const u32x4 f1 = {pk[4], pk[5], pk[6], pk[7]};
      const u32x4 f2 = {pk[8], pk[9], pk[10], pk[11]};
      const u32x4 f3 = {pk[12], pk[13], pk[14], pk[15]};
      const bf16x8 pa0 = __builtin_bit_cast(bf16x8, f0);
      const bf16x8 pa1 = __builtin_bit_cast(bf16x8, f1);
      const bf16x8 pa2 = __builtin_bit_cast(bf16x8, f2);
      const bf16x8 pa3 = __builtin_bit_cast(bf16x8, f3);

      // ---- PV cluster: boost priority while feeding the matrix pipe ----
      __builtin_amdgcn_s_setprio(1);
#pragma unroll
      for (int ks = 0; ks < 4; ++ks) {
        if (!(skipHi && ks >= 2)) {
          const bf16x8 pa = (ks == 0) ? pa0 : (ks == 1) ? pa1 : (ks == 2) ? pa2 : pa3;
          const bf16x8 va0 = *reinterpret_cast<const bf16x8*>(&Vt[l31][ks * 16 + hi2 * 8]);
          const bf16x8 va1 = *reinterpret_cast<const bf16x8*>(&Vt[32 + l31][ks * 16 + hi2 * 8]);
          y0 = __builtin_amdgcn_mfma_f32_32x32x16_bf16(va0, pa, y0, 0, 0, 0);
          y1 = __builtin_amdgcn_mfma_f32_32x32x16_bf16(va1, pa, y1, 0, 0, 0);
        }
      }
      __builtin_amdgcn_s_setprio(0);
    };

    for (int tt = w; tt < NT; tt += 4) {
      stageV(tt);
      bf16x8 kr[8];
      {
        const bf16* kp = K + (rb + tt * 64 + l31) * 1024 + hcol + hi2 * 8;
        const bf16* kp2 = kp + (size_t)32 * 1024;
#pragma unroll
        for (int i = 0; i < 4; ++i) {
          kr[i] = *reinterpret_cast<const bf16x8*>(kp + i * 16);
          kr[4 + i] = *reinterpret_cast<const bf16x8*>(kp2 + i * 16);
        }
      }
      const bool diag = (tt == qg);

      // ---- QK^T cluster: boost priority while feeding the matrix pipe ----
      __builtin_amdgcn_s_setprio(1);
      f32x16 sA0 = {}, sA1, sB0 = {}, sB1 = {};
      sA0 = __builtin_amdgcn_mfma_f32_32x32x16_bf16(kr[0], qfA[0], sA0, 0, 0, 0);
      sA0 = __builtin_amdgcn_mfma_f32_32x32x16_bf16(kr[1], qfA[1], sA0, 0, 0, 0);
      sA0 = __builtin_amdgcn_mfma_f32_32x32x16_bf16(kr[2], qfA[2], sA0, 0, 0, 0);
      sA0 = __builtin_amdgcn_mfma_f32_32x32x16_bf16(kr[3], qfA[3], sA0, 0, 0, 0);
      if (!diag) {
        f32x16 t0 = {};
        t0 = __builtin_amdgcn_mfma_f32_32x32x16_bf16(kr[4], qfA[0], t0, 0, 0, 0);
        t0 = __builtin_amdgcn_mfma_f32_32x32x16_bf16(kr[5], qfA[1], t0, 0, 0, 0);
        t0 = __builtin_amdgcn_mfma_f32_32x32x16_bf16(kr[6], qfA[2], t0, 0, 0, 0);
        t0 = __builtin_amdgcn_mfma_f32_32x32x16_bf16(kr[7], qfA[3], t0, 0, 0, 0);
        sA1 = t0;
      } else {
#pragma unroll
        for (int r = 0; r < 16; ++r) sA1[r] = -INFINITY;  // kv-high > all A rows
      }
      sB0 = __builtin_amdgcn_mfma_f32_32x32x16_bf16(kr[0], qfB[0], sB0, 0, 0, 0);
      sB0 = __builtin_amdgcn_mfma_f32_32x32x16_bf16(kr[1], qfB[1], sB0, 0, 0, 0);
      sB0 = __builtin_amdgcn_mfma_f32_32x32x16_bf16(kr[2], qfB[2], sB0, 0, 0, 0);
      sB0 = __builtin_amdgcn_mfma_f32_32x32x16_bf16(kr[3], qfB[3], sB0, 0, 0, 0);
      sB1 = __builtin_amdgcn_mfma_f32_32x32x16_bf16(kr[4], qfB[0], sB1, 0, 0, 0);
      sB1 = __builtin_amdgcn_mfma_f32_32x32x16_bf16(kr[5], qfB[1], sB1, 0, 0, 0);
      sB1 = __builtin_amdgcn_mfma_f32_32x32x16_bf16(kr[6], qfB[2], sB1, 0, 0, 0);
      sB1 = __builtin_amdgcn_mfma_f32_32x32x16_bf16(kr[7], qfB[3], sB1, 0, 0, 0);
      __builtin_amdgcn_s_setprio(0);

      if (diag) {
#pragma unroll
        for (int r = 0; r < 16; ++r) {
          const int kvl = (r & 3) + 8 * (r >> 2) + 4 * hi2;
          if (kvl > l31) sA0[r] = -INFINITY;  // A diag in kv-low
          if (kvl > l31) sB1[r] = -INFINITY;  // B diag in kv-high
        }
      }

      smax_pv64(sA0, sA1, mA, lA, yA0, yA1, diag);
      smax_pv64(sB0, sB1, mB, lB, yB0, yB1, false);
    }

    // ---- combine 4 wave-partials: 2 merged phases (A pair, B pair) ----
    __syncthreads();  // Vt dead; comb may alias it
    if (lane < 32) {
      mlS[w][0][l31] = mA;
      mlS[w][1][l31] = lA;
      mlS[w][0][32 + l31] = mB;
      mlS[w][1][32 + l31] = lB;
    }

    auto comb_pair = [&](const f32x16& y0, const f32x16& y1, int qoff) {
#pragma unroll
      for (int r = 0; r < 16; r += 2) {
        const int d0 = (r & 3) + 8 * (r >> 2) + 4 * hi2;
        float2 v2a;
        v2a.x = y0[r];
        v2a.y = y0[r + 1];
        *reinterpret_cast<float2*>(&combf[((size_t)w * 32 + l31) * 66 + d0]) = v2a;
        float2 v2b;
        v2b.x = y1[r];
        v2b.y = y1[r + 1];
        *reinterpret_cast<float2*>(&combf[((size_t)w * 32 + l31) * 66 + d0 + 32]) = v2b;
      }
      __syncthreads();

      const int tq = tid >> 3;       // 0..31 (q row within set)
      const int dg = (tid & 7) * 8;  // 0..56 (d offset, 8 floats/thread)
      float mw[4], lw[4];
#pragma unroll
      for (int ww = 0; ww < 4; ++ww) {
        mw[ww] = mlS[ww][0][qoff + tq];
        lw[ww] = mlS[ww][1][qoff + tq];
      }
      const float M = fmaxf(fmaxf(mw[0], mw[1]), fmaxf(mw[2], mw[3]));
      float wg[4];
      float Lsum = 0.f;
#pragma unroll
      for (int ww = 0; ww < 4; ++ww) {
        wg[ww] = fexp2((mw[ww] - M) * cl2);
        Lsum += lw[ww] * wg[ww];
      }
      const float inv = 1.f / Lsum;
      float a8[8] = {};
#pragma unroll
      for (int ww = 0; ww < 4; ++ww)
#pragma unroll
        for (int jj = 0; jj < 8; ++jj)
          a8[jj] += wg[ww] * combf[((size_t)ww * 32 + tq) * 66 + dg + jj];
      bf16x8 o;
#pragma unroll
      for (int jj = 0; jj < 8; ++jj) o[jj] = (bf16)(a8[jj] * inv);
      *reinterpret_cast<bf16x8*>(Y + (rb + qbase + qoff + tq) * 1024 + hcol + dg) = o;
      __syncthreads();
    };

    comb_pair(yA0, yA1, 0);
    comb_pair(yB0, yB1, 32);
  };

  run(31 - jp);
  run(jp);
}

// ---------------- host launch ----------------------------------------------
extern "C" void kernel_launch(void* const* d_in, const int* in_sizes, int n_in,
                              void* d_out, int out_size, void* d_ws,
                              size_t ws_size, hipStream_t stream) {
  const float* x = (const float*)d_in[0];
  const float* Wq = (const float*)d_in[1];
  const float* bq = (const float*)d_in[2];
  const float* Wk = (const float*)d_in[3];
  const float* bk = (const float*)d_in[4];
  const float* Wv = (const float*)d_in[5];
  const float* bv = (const float*)d_in[6];
  const float* Wp = (const float*)d_in[7];
  const float* bp = (const float*)d_in[8];

  const int BS = 4096;
  const int Dm = 1024;

  char* ws = (char*)d_ws;
  bf16* xb = (bf16*)(ws);
  bf16* wqb = (bf16*)(ws + (size_t)(8 << 20));
  bf16* wkb = (bf16*)(ws + (size_t)(10 << 20));
  bf16* wvb = (bf16*)(ws + (size_t)(12 << 20));
  bf16* wpb = (bf16*)(ws + (size_t)(14 << 20));
  bf16* Qb = (bf16*)(ws + (size_t)(16 << 20));
  bf16* Kb = (bf16*)(ws + (size_t)(24 << 20));
  bf16* Vb = (bf16*)(ws + (size_t)(32 << 20));
  bf16* Yb = (bf16*)(ws + (size_t)(40 << 20));

  CvtArgs ca;
  ca.src[0] = x;  ca.dst[0] = xb;  ca.n[0] = BS * Dm;
  ca.src[1] = Wq; ca.dst[1] = wqb; ca.n[1] = Dm * Dm;
  ca.src[2] = Wk; ca.dst[2] = wkb; ca.n[2] = Dm * Dm;
  ca.src[3] = Wv; ca.dst[3] = wvb; ca.n[3] = Dm * Dm;
  ca.src[4] = Wp; ca.dst[4] = wpb; ca.n[4] = Dm * Dm;
  cvt_multi<<<dim3(1024, 5), 256, 0, stream>>>(ca);

  GemmBatch gq;
  gq.Bw[0] = wqb; gq.bias[0] = bq; gq.C[0] = Qb;
  gq.Bw[1] = wkb; gq.bias[1] = bk; gq.C[1] = Kb;
  gq.Bw[2] = wvb; gq.bias[2] = bv; gq.C[2] = Vb;
  gemm128<true><<<dim3(32, 8, 3), 256, 0, stream>>>(xb, gq, BS, Dm, Dm);

  attn_ws<<<dim3(512), 256, 0, stream>>>(Qb, Kb, Vb, Yb);

  GemmBatch gp;
  gp.Bw[0] = wpb; gp.bias[0] = bp; gp.C[0] = d_out;
  gp.Bw[1] = wpb; gp.bias[1] = bp; gp.C[1] = d_out;
  gp.Bw[2] = wpb; gp.bias[2] = bp; gp.C[2] = d_out;
  gemm128<false><<<dim3(32, 8, 1), 256, 0, stream>>>(Yb, gp, BS, Dm, Dm);
}